// Round 4
// baseline (1093.788 us; speedup 1.0000x reference)
//
#include <hip/hip_runtime.h>
#include <hip/hip_cooperative_groups.h>
#include <hip/hip_bf16.h>
#include <math.h>

// GCN 5-layer: dims 16->64->128->256->512->1, N=20000, E=320000.
// Round 13: single cooperative mega-kernel. The 12-dispatch pipeline is a
// strict chain; r12's per-kernel cost model leaves ~100us unexplained and it
// tracks dispatch count -> theory: inter-dispatch overhead. One kernel,
// 256 blocks x 512 threads (1 block/CU co-resident), grid.sync() between
// phases. k_deg deleted (dinv = rsqrtf(cnt+1) inline, identical bits).
// Per-phase math is bit-identical to r12 (minus the dropped XCD slicing,
// which measured null).

#define ELLW 64   // P(in-deg >= 48) ~ 1e-10 for Poisson(16)
#define GBM 128
#define GBK 32
#define LDSS 40   // LDS row stride in elements (80B, 16B-aligned)
#define NBLK 256
#define NTHR 512

namespace cg = cooperative_groups;

typedef __attribute__((ext_vector_type(8))) short short8;
typedef __attribute__((ext_vector_type(4))) float f32x4;

__device__ __forceinline__ ushort f2bf(float f) {
    __hip_bfloat16 h = __float2bfloat16(f);   // RNE
    return *(ushort*)&h;
}

__device__ __forceinline__ float bf2f(short s) {
    union { unsigned int u; float f; } c;
    c.u = ((unsigned int)(unsigned short)s) << 16;
    return c.f;
}

__device__ __forceinline__ float dinv_of(const int* __restrict__ cnt, int v) {
    return rsqrtf((float)(cnt[v] + 1));       // in-degree + self-loop
}

struct MegaArgs {
    const float* x; const int* e_row; const int* e_col;
    const float* W1; const float* b1;   // 16x64
    const float* W2; const float* b2;   // 64x128
    const float* W3; const float* b3;   // 128x256
    const float* W4; const float* b4;   // 256x512
    const float* W5; const float* b5;   // 512x1
    ushort* bufA; ushort* bufB; float* z;
    int* cnt; int* ell;
    ushort* wt2; ushort* wt3; ushort* wt4;  // bf16 transposed weights (MFMA B)
    float* outp;
    int n; int E;
};

// ---- bf16 ELL aggregation (layers 2..4), unroll-8, dinv inline -------------
__device__ void agg_phase(const short8* __restrict__ h, short8* __restrict__ out,
                          const int* __restrict__ ell, const int* __restrict__ cnt,
                          int n, int g_shift, int bid, int tid) {
    int g = 1 << g_shift;
    int npb = NTHR >> g_shift;                 // nodes per block-iter
    int grp = tid >> g_shift;
    int lane = tid & (g - 1);
    int iters = (n + NBLK * npb - 1) / (NBLK * npb);
    for (int u = 0; u < iters; u++) {
        int v = (u * NBLK + bid) * npb + grp;
        if (v >= n) continue;
        float dv = dinv_of(cnt, v);
        int end = cnt[v];
        float inv_cnt = 1.0f / (float)(end + 1);
        const int* r = ell + ((size_t)v << 6);

        float acc[8];
        short8 hv = h[(size_t)v * g + lane];
        #pragma unroll
        for (int i = 0; i < 8; i++) acc[i] = dv * bf2f(hv[i]);

        int e = 0;
        for (; e + 8 <= end; e += 8) {
            int s0 = r[e],     s1 = r[e + 1], s2 = r[e + 2], s3 = r[e + 3];
            int s4 = r[e + 4], s5 = r[e + 5], s6 = r[e + 6], s7 = r[e + 7];
            short8 h0 = h[(size_t)s0 * g + lane];
            short8 h1 = h[(size_t)s1 * g + lane];
            short8 h2 = h[(size_t)s2 * g + lane];
            short8 h3 = h[(size_t)s3 * g + lane];
            short8 h4 = h[(size_t)s4 * g + lane];
            short8 h5 = h[(size_t)s5 * g + lane];
            short8 h6 = h[(size_t)s6 * g + lane];
            short8 h7 = h[(size_t)s7 * g + lane];
            float w0 = dinv_of(cnt, s0), w1 = dinv_of(cnt, s1);
            float w2 = dinv_of(cnt, s2), w3 = dinv_of(cnt, s3);
            float w4 = dinv_of(cnt, s4), w5 = dinv_of(cnt, s5);
            float w6 = dinv_of(cnt, s6), w7 = dinv_of(cnt, s7);
            #pragma unroll
            for (int i = 0; i < 8; i++)
                acc[i] += w0 * bf2f(h0[i]) + w1 * bf2f(h1[i])
                        + w2 * bf2f(h2[i]) + w3 * bf2f(h3[i])
                        + w4 * bf2f(h4[i]) + w5 * bf2f(h5[i])
                        + w6 * bf2f(h6[i]) + w7 * bf2f(h7[i]);
        }
        for (; e + 4 <= end; e += 4) {
            int s0 = r[e], s1 = r[e + 1], s2 = r[e + 2], s3 = r[e + 3];
            short8 h0 = h[(size_t)s0 * g + lane];
            short8 h1 = h[(size_t)s1 * g + lane];
            short8 h2 = h[(size_t)s2 * g + lane];
            short8 h3 = h[(size_t)s3 * g + lane];
            float w0 = dinv_of(cnt, s0), w1 = dinv_of(cnt, s1);
            float w2 = dinv_of(cnt, s2), w3 = dinv_of(cnt, s3);
            #pragma unroll
            for (int i = 0; i < 8; i++)
                acc[i] += w0 * bf2f(h0[i]) + w1 * bf2f(h1[i])
                        + w2 * bf2f(h2[i]) + w3 * bf2f(h3[i]);
        }
        for (; e < end; e++) {
            int s0 = r[e];
            float w0 = dinv_of(cnt, s0);
            short8 h0 = h[(size_t)s0 * g + lane];
            #pragma unroll
            for (int i = 0; i < 8; i++) acc[i] += w0 * bf2f(h0[i]);
        }
        float sc = dv * inv_cnt;
        short8 o;
        #pragma unroll
        for (int i = 0; i < 8; i++) o[i] = (short)f2bf(acc[i] * sc);
        out[(size_t)v * g + lane] = o;
    }
}

// ---- MFMA GEMM phase: two independent 256-thread groups per block ----------
// K in {64,128,256}, Ndim multiple of 128, M padded to 128 -> no bounds checks
// on loads. Invalid (out-of-range) groups redundantly compute tile 0 with
// stores masked, keeping barrier counts uniform across the block.
__device__ void gemm_phase(const ushort* __restrict__ A, const ushort* __restrict__ Wt,
                           const float* __restrict__ bias, ushort* __restrict__ C,
                           int K, int nxt, int ntiles,
                           ushort* As, ushort* Bs, int gid, int ltid) {
    int wave = ltid >> 6, lane = ltid & 63;
    int wr = wave >> 1, wc = wave & 1;
    int q = lane >> 4, mr = lane & 15;
    int sr = ltid >> 2, skoff = (ltid & 3) * 8;
    int Ndim = nxt << 7;
    int uiter = (ntiles + 2 * NBLK - 1) / (2 * NBLK);
    for (int u = 0; u < uiter; u++) {
        int tile = u * 2 * NBLK + gid;
        bool valid = tile < ntiles;
        int teff = valid ? tile : 0;
        int bx = teff % nxt, by = teff / nxt;
        int row0 = by << 7, col0 = bx << 7;

        __syncthreads();                 // protect LDS reuse across u / phases
        f32x4 acc[4][4];
        #pragma unroll
        for (int i = 0; i < 4; i++)
            #pragma unroll
            for (int j = 0; j < 4; j++) acc[i][j] = (f32x4){0.f, 0.f, 0.f, 0.f};

        short8 va0 = *(const short8*)(A + (size_t)(row0 + sr) * K + skoff);
        short8 va1 = *(const short8*)(A + (size_t)(row0 + sr + 64) * K + skoff);
        short8 vb0 = *(const short8*)(Wt + (size_t)(col0 + sr) * K + skoff);
        short8 vb1 = *(const short8*)(Wt + (size_t)(col0 + sr + 64) * K + skoff);
        *(short8*)(As + sr * LDSS + skoff) = va0;
        *(short8*)(As + (sr + 64) * LDSS + skoff) = va1;
        *(short8*)(Bs + sr * LDSS + skoff) = vb0;
        *(short8*)(Bs + (sr + 64) * LDSS + skoff) = vb1;
        __syncthreads();

        for (int k0 = 0;;) {
            int k1 = k0 + GBK;
            bool more = (k1 < K);
            if (more) {                  // reg-prefetch next K-tile
                int gk = k1 + skoff;
                va0 = *(const short8*)(A + (size_t)(row0 + sr) * K + gk);
                va1 = *(const short8*)(A + (size_t)(row0 + sr + 64) * K + gk);
                vb0 = *(const short8*)(Wt + (size_t)(col0 + sr) * K + gk);
                vb1 = *(const short8*)(Wt + (size_t)(col0 + sr + 64) * K + gk);
            }
            short8 afr[4], bfr[4];
            #pragma unroll
            for (int i = 0; i < 4; i++)
                afr[i] = *(const short8*)(As + (wr * 64 + i * 16 + mr) * LDSS + q * 8);
            #pragma unroll
            for (int j = 0; j < 4; j++)
                bfr[j] = *(const short8*)(Bs + (wc * 64 + j * 16 + mr) * LDSS + q * 8);
            #pragma unroll
            for (int i = 0; i < 4; i++)
                #pragma unroll
                for (int j = 0; j < 4; j++)
                    acc[i][j] = __builtin_amdgcn_mfma_f32_16x16x32_bf16(afr[i], bfr[j],
                                                                        acc[i][j], 0, 0, 0);
            if (!more) break;
            __syncthreads();
            *(short8*)(As + sr * LDSS + skoff) = va0;
            *(short8*)(As + (sr + 64) * LDSS + skoff) = va1;
            *(short8*)(Bs + sr * LDSS + skoff) = vb0;
            *(short8*)(Bs + (sr + 64) * LDSS + skoff) = vb1;
            __syncthreads();
            k0 = k1;
        }

        if (valid) {   // epilogue: col=lane&15, row=q*4+reg; bias+relu, bf16
            #pragma unroll
            for (int j = 0; j < 4; j++) {
                int col = col0 + wc * 64 + j * 16 + mr;
                float bj = bias[col];
                #pragma unroll
                for (int i = 0; i < 4; i++) {
                    int rbase = row0 + wr * 64 + i * 16 + q * 4;
                    #pragma unroll
                    for (int r = 0; r < 4; r++) {
                        float vv = acc[i][j][r] + bj;
                        C[(size_t)(rbase + r) * Ndim + col] = f2bf(fmaxf(vv, 0.0f));
                    }
                }
            }
        }
    }
}

// ---------------- the mega-kernel ----------------

__global__ __launch_bounds__(NTHR, 2) void mega(MegaArgs a) {
    cg::grid_group grid = cg::this_grid();
    __shared__ __align__(16) ushort sAB[2][2][GBM * LDSS];   // 40 KB
    int bid = blockIdx.x, tid = threadIdx.x;
    int gtid = bid * NTHR + tid;
    const int gsize = NBLK * NTHR;                            // 131072

    // ---- P1: zero cnt + bf16 weight transposes (8192 | 32768 | 131072) ----
    for (int i = gtid; i < 172032; i += gsize) {
        if (i < a.n) a.cnt[i] = 0;
        const float* W; ushort* T; int K, N, j;
        if (i < 8192)        { W = a.W2; T = a.wt2; K = 64;  N = 128; j = i; }
        else if (i < 40960)  { W = a.W3; T = a.wt3; K = 128; N = 256; j = i - 8192; }
        else                 { W = a.W4; T = a.wt4; K = 256; N = 512; j = i - 40960; }
        int nn = j / K, kk = j - nn * K;
        T[(size_t)nn * K + kk] = f2bf(W[(size_t)kk * N + nn]);
    }
    __threadfence(); grid.sync();

    // ---- P2: ELL build (count + fill) ----
    for (int e = gtid; e < a.E; e += gsize) {
        int s = a.e_row[e], d = a.e_col[e];
        int pos = atomicAdd(&a.cnt[d], 1);
        a.ell[((size_t)d << 6) + pos] = s;
    }
    __threadfence(); grid.sync();

    // ---- P3: layer 1 fused agg(d=16, fp32) + 16x64 GEMM + relu ----
    {
        int halfid = tid >> 8, htid = tid & 255;
        float* fb0 = (float*)(&sAB[halfid][0][0]);
        float* sW = fb0;                                 // 1024
        float* sb = fb0 + 1024;                          // 64
        float (*sagg)[17] = (float(*)[17])(fb0 + 1088);  // 64 x 17
        for (int i = htid; i < 1024; i += 256) sW[i] = a.W1[i];
        if (htid < 64) sb[htid] = a.b1[htid];
        int grp = htid >> 2, l4 = htid & 3;
        int v = bid * 128 + halfid * 64 + grp;
        if (v < a.n) {
            const float4* xx = (const float4*)a.x;
            float dv = dinv_of(a.cnt, v);
            int end = a.cnt[v];
            float inv_cnt = 1.0f / (float)(end + 1);
            const int* r = a.ell + ((size_t)v << 6);
            float4 hv = xx[(size_t)v * 4 + l4];
            float4 acc = make_float4(dv * hv.x, dv * hv.y, dv * hv.z, dv * hv.w);
            int e = 0;
            for (; e + 8 <= end; e += 8) {
                int s0 = r[e],     s1 = r[e + 1], s2 = r[e + 2], s3 = r[e + 3];
                int s4 = r[e + 4], s5 = r[e + 5], s6 = r[e + 6], s7 = r[e + 7];
                float4 h0 = xx[(size_t)s0 * 4 + l4];
                float4 h1 = xx[(size_t)s1 * 4 + l4];
                float4 h2 = xx[(size_t)s2 * 4 + l4];
                float4 h3 = xx[(size_t)s3 * 4 + l4];
                float4 h4 = xx[(size_t)s4 * 4 + l4];
                float4 h5 = xx[(size_t)s5 * 4 + l4];
                float4 h6 = xx[(size_t)s6 * 4 + l4];
                float4 h7 = xx[(size_t)s7 * 4 + l4];
                float w0 = dinv_of(a.cnt, s0), w1 = dinv_of(a.cnt, s1);
                float w2 = dinv_of(a.cnt, s2), w3 = dinv_of(a.cnt, s3);
                float w4 = dinv_of(a.cnt, s4), w5 = dinv_of(a.cnt, s5);
                float w6 = dinv_of(a.cnt, s6), w7 = dinv_of(a.cnt, s7);
                acc.x += w0 * h0.x + w1 * h1.x + w2 * h2.x + w3 * h3.x
                       + w4 * h4.x + w5 * h5.x + w6 * h6.x + w7 * h7.x;
                acc.y += w0 * h0.y + w1 * h1.y + w2 * h2.y + w3 * h3.y
                       + w4 * h4.y + w5 * h5.y + w6 * h6.y + w7 * h7.y;
                acc.z += w0 * h0.z + w1 * h1.z + w2 * h2.z + w3 * h3.z
                       + w4 * h4.z + w5 * h5.z + w6 * h6.z + w7 * h7.z;
                acc.w += w0 * h0.w + w1 * h1.w + w2 * h2.w + w3 * h3.w
                       + w4 * h4.w + w5 * h5.w + w6 * h6.w + w7 * h7.w;
            }
            for (; e + 4 <= end; e += 4) {
                int s0 = r[e], s1 = r[e + 1], s2 = r[e + 2], s3 = r[e + 3];
                float4 h0 = xx[(size_t)s0 * 4 + l4];
                float4 h1 = xx[(size_t)s1 * 4 + l4];
                float4 h2 = xx[(size_t)s2 * 4 + l4];
                float4 h3 = xx[(size_t)s3 * 4 + l4];
                float w0 = dinv_of(a.cnt, s0), w1 = dinv_of(a.cnt, s1);
                float w2 = dinv_of(a.cnt, s2), w3 = dinv_of(a.cnt, s3);
                acc.x += w0 * h0.x + w1 * h1.x + w2 * h2.x + w3 * h3.x;
                acc.y += w0 * h0.y + w1 * h1.y + w2 * h2.y + w3 * h3.y;
                acc.z += w0 * h0.z + w1 * h1.z + w2 * h2.z + w3 * h3.z;
                acc.w += w0 * h0.w + w1 * h1.w + w2 * h2.w + w3 * h3.w;
            }
            for (; e < end; e++) {
                int s = r[e];
                float w = dinv_of(a.cnt, s);
                float4 hs = xx[(size_t)s * 4 + l4];
                acc.x += w * hs.x; acc.y += w * hs.y; acc.z += w * hs.z; acc.w += w * hs.w;
            }
            float sc = dv * inv_cnt;
            sagg[grp][l4 * 4 + 0] = acc.x * sc;
            sagg[grp][l4 * 4 + 1] = acc.y * sc;
            sagg[grp][l4 * 4 + 2] = acc.z * sc;
            sagg[grp][l4 * 4 + 3] = acc.w * sc;
        }
        __syncthreads();
        int c0 = (htid & 3) * 16;
        if (v < a.n) {
            float o[16];
            #pragma unroll
            for (int jj = 0; jj < 16; jj++) o[jj] = sb[c0 + jj];
            #pragma unroll
            for (int k = 0; k < 16; k++) {
                float aa = sagg[grp][k];
                #pragma unroll
                for (int jj = 0; jj < 16; jj++) o[jj] += aa * sW[k * 64 + c0 + jj];
            }
            short8 p0, p1;
            #pragma unroll
            for (int jj = 0; jj < 8; jj++) p0[jj] = (short)f2bf(fmaxf(o[jj], 0.0f));
            #pragma unroll
            for (int jj = 0; jj < 8; jj++) p1[jj] = (short)f2bf(fmaxf(o[jj + 8], 0.0f));
            *(short8*)(a.bufA + (size_t)v * 64 + c0) = p0;
            *(short8*)(a.bufA + (size_t)v * 64 + c0 + 8) = p1;
        }
    }
    __threadfence(); grid.sync();

    int gid = bid * 2 + (tid >> 8);
    int ltid = tid & 255;
    ushort* As = &sAB[tid >> 8][0][0];
    ushort* Bs = &sAB[tid >> 8][1][0];
    int mt = (a.n + 127) >> 7;                 // 157 row-tiles (M padded)

    // ---- layer 2 ----
    agg_phase((const short8*)a.bufA, (short8*)a.bufB, a.ell, a.cnt, a.n, 3, bid, tid);
    __threadfence(); grid.sync();
    gemm_phase(a.bufB, a.wt2, a.b2, a.bufA, 64, 1, mt * 1, As, Bs, gid, ltid);
    __threadfence(); grid.sync();

    // ---- layer 3 ----
    agg_phase((const short8*)a.bufA, (short8*)a.bufB, a.ell, a.cnt, a.n, 4, bid, tid);
    __threadfence(); grid.sync();
    gemm_phase(a.bufB, a.wt3, a.b3, a.bufA, 128, 2, mt * 2, As, Bs, gid, ltid);
    __threadfence(); grid.sync();

    // ---- layer 4 ----
    agg_phase((const short8*)a.bufA, (short8*)a.bufB, a.ell, a.cnt, a.n, 5, bid, tid);
    __threadfence(); grid.sync();
    gemm_phase(a.bufB, a.wt4, a.b4, a.bufA, 256, 4, mt * 4, As, Bs, gid, ltid);
    __threadfence(); grid.sync();

    // ---- layer 5a: z[v] = dot(h4[v], w5) ----
    for (int u = 0; u < 10; u++) {
        int wv = (u * NBLK + bid) * 8 + (tid >> 6);
        if (wv >= a.n) continue;
        int lane = tid & 63;
        short8 av = ((const short8*)a.bufA)[(size_t)wv * 64 + lane];
        const float4* wp = (const float4*)a.W5;
        float4 w0 = wp[lane * 2], w1 = wp[lane * 2 + 1];
        float acc = bf2f(av[0]) * w0.x + bf2f(av[1]) * w0.y
                  + bf2f(av[2]) * w0.z + bf2f(av[3]) * w0.w
                  + bf2f(av[4]) * w1.x + bf2f(av[5]) * w1.y
                  + bf2f(av[6]) * w1.z + bf2f(av[7]) * w1.w;
        #pragma unroll
        for (int off = 32; off > 0; off >>= 1) acc += __shfl_down(acc, off, 64);
        if (lane == 0) a.z[wv] = acc;
    }
    __threadfence(); grid.sync();

    // ---- layer 5b: add-aggregate + sigmoid ----
    for (int v = gtid; v < a.n; v += gsize) {
        float dv = dinv_of(a.cnt, v);
        float acc = dv * a.z[v];
        int end = a.cnt[v];
        const int* r = a.ell + ((size_t)v << 6);
        for (int e = 0; e < end; e++) {
            int s = r[e];
            acc += dinv_of(a.cnt, s) * a.z[s];
        }
        float rr = dv * acc + a.b5[0];
        a.outp[v] = 1.0f / (1.0f + expf(-rr));
    }
}

// ---------------- launch ----------------

extern "C" void kernel_launch(void* const* d_in, const int* in_sizes, int n_in,
                              void* d_out, int out_size, void* d_ws, size_t ws_size,
                              hipStream_t stream) {
    const int n = in_sizes[0] / 16;
    const int E = in_sizes[1] / 2;
    const int* ei = (const int*)d_in[1];

    // workspace layout
    float* bufA_f = (float*)d_ws;                       // n*512 floats
    float* bufB_f = bufA_f + (size_t)n * 512;           // n*512 floats
    int*   cnt    = (int*)(bufB_f + (size_t)n * 512);   // n
    int*   ell    = cnt + n;                            // n * ELLW
    ushort* wt2   = (ushort*)(ell + (size_t)n * ELLW);
    ushort* wt3   = wt2 + 64 * 128;
    ushort* wt4   = wt3 + 128 * 256;

    MegaArgs ha;
    ha.x = (const float*)d_in[0];
    ha.e_row = ei; ha.e_col = ei + E;
    ha.W1 = (const float*)d_in[2];  ha.b1 = (const float*)d_in[3];
    ha.W2 = (const float*)d_in[4];  ha.b2 = (const float*)d_in[5];
    ha.W3 = (const float*)d_in[6];  ha.b3 = (const float*)d_in[7];
    ha.W4 = (const float*)d_in[8];  ha.b4 = (const float*)d_in[9];
    ha.W5 = (const float*)d_in[10]; ha.b5 = (const float*)d_in[11];
    ha.bufA = (ushort*)bufA_f;
    ha.bufB = (ushort*)bufB_f;
    ha.z = bufB_f;                                      // reused after last agg
    ha.cnt = cnt; ha.ell = ell;
    ha.wt2 = wt2; ha.wt3 = wt3; ha.wt4 = wt4;
    ha.outp = (float*)d_out;
    ha.n = n; ha.E = E;

    void* kargs[] = { (void*)&ha };
    hipLaunchCooperativeKernel((const void*)mega, dim3(NBLK), dim3(NTHR),
                               kargs, 0, stream);
}

// Round 5
// 208.708 us; speedup vs baseline: 5.2407x; 5.2407x over previous
//
#include <hip/hip_runtime.h>
#include <hip/hip_bf16.h>
#include <math.h>

// GCN 5-layer: dims 16->64->128->256->512->1, N=20000, E=320000.
// Round 14: revert to r12 multi-kernel (r13 coop mega collapsed occupancy ->
// 5x regression). Changes vs r12: (a) dot512 fused into GEMM-4 epilogue
// (shfl-reduce + atomicAdd per row; kills 1 dispatch + 41 MB traffic),
// (b) weight transposes ride k_fill_ell's grid, prep0 = cnt-zero only,
// (c) z buffer zeroed in k_deg. Aggs/GEMM body bit-identical to r12.

#define N_NODES 20000
#define N_EDGES 320000
#define ELLW 64   // P(in-deg >= 48) ~ 1e-10 for Poisson(16)

typedef __attribute__((ext_vector_type(8))) short short8;
typedef __attribute__((ext_vector_type(4))) float f32x4;

__device__ inline ushort f2bf(float f) {
    __hip_bfloat16 h = __float2bfloat16(f);   // RNE
    return *(ushort*)&h;
}

__device__ inline float bf2f(short s) {
    union { unsigned int u; float f; } c;
    c.u = ((unsigned int)(unsigned short)s) << 16;
    return c.f;
}

// ---------------- prep0: zero cnt only ----------------

__global__ void k_zero(int* __restrict__ cnt, int n) {
    int i = blockIdx.x * blockDim.x + threadIdx.x;
    if (i < n) cnt[i] = 0;
}

// ---------------- ELL build + weight transposes (ride the same grid) --------
// transpose segments (N*K): 8192 | 32768 | 131072 -> total 172032 < E

__global__ void k_fill_ell(const int* __restrict__ row, const int* __restrict__ col,
                           int* __restrict__ cnt, int* __restrict__ ell, int E,
                           const float* __restrict__ W2, const float* __restrict__ W3,
                           const float* __restrict__ W4,
                           ushort* __restrict__ T2, ushort* __restrict__ T3,
                           ushort* __restrict__ T4) {
    int e = blockIdx.x * blockDim.x + threadIdx.x;
    if (e < 172032) {
        const float* W; ushort* T; int K, N, j;
        if (e < 8192)        { W = W2; T = T2; K = 64;  N = 128; j = e; }
        else if (e < 40960)  { W = W3; T = T3; K = 128; N = 256; j = e - 8192; }
        else                 { W = W4; T = T4; K = 256; N = 512; j = e - 40960; }
        int nn = j / K, kk = j - nn * K;
        T[(size_t)nn * K + kk] = f2bf(W[(size_t)kk * N + nn]);
    }
    if (e >= E) return;
    int s = row[e], d = col[e];
    int pos = atomicAdd(&cnt[d], 1);
    ell[((size_t)d << 6) + pos] = s;
}

__global__ void k_deg(const int* __restrict__ cnt, float* __restrict__ dinv,
                      float* __restrict__ z, int n, int mpad) {
    int v = blockIdx.x * blockDim.x + threadIdx.x;
    if (v < n) dinv[v] = rsqrtf((float)(cnt[v] + 1));   // in-degree + self-loop
    if (v < mpad) z[v] = 0.0f;
}

// ---------------- layer 1 fused: agg(d=16, fp32) + GEMM 16x64 + relu --------
// 256 threads = 64 nodes/block (4 lanes/node for agg, 4 col-groups/node GEMM).

__global__ __launch_bounds__(256) void k_l1_fused(const float4* __restrict__ x,
                                                  ushort* __restrict__ h_out,
                                                  const int* __restrict__ ell,
                                                  const int* __restrict__ cnt,
                                                  const float* __restrict__ dinv,
                                                  const float* __restrict__ W,
                                                  const float* __restrict__ b, int n) {
    __shared__ float sW[16 * 64];
    __shared__ float sb[64];
    __shared__ float sagg[64][17];    // padded: avoid bank conflicts
    int tid = threadIdx.x;
    #pragma unroll
    for (int i = tid; i < 1024; i += 256) sW[i] = W[i];
    if (tid < 64) sb[tid] = b[tid];

    int grp = tid >> 2;               // node within block
    int lane = tid & 3;               // float4 lane (4 feats each)
    int v = blockIdx.x * 64 + grp;
    if (v < n) {
        float dv = dinv[v];
        int end = cnt[v];
        float inv_cnt = 1.0f / (float)(end + 1);
        const int* r = ell + ((size_t)v << 6);
        float4 hv = x[(size_t)v * 4 + lane];
        float4 acc = make_float4(dv * hv.x, dv * hv.y, dv * hv.z, dv * hv.w);
        int e = 0;
        for (; e + 8 <= end; e += 8) {
            int s0 = r[e],     s1 = r[e + 1], s2 = r[e + 2], s3 = r[e + 3];
            int s4 = r[e + 4], s5 = r[e + 5], s6 = r[e + 6], s7 = r[e + 7];
            float4 h0 = x[(size_t)s0 * 4 + lane];
            float4 h1 = x[(size_t)s1 * 4 + lane];
            float4 h2 = x[(size_t)s2 * 4 + lane];
            float4 h3 = x[(size_t)s3 * 4 + lane];
            float4 h4 = x[(size_t)s4 * 4 + lane];
            float4 h5 = x[(size_t)s5 * 4 + lane];
            float4 h6 = x[(size_t)s6 * 4 + lane];
            float4 h7 = x[(size_t)s7 * 4 + lane];
            float w0 = dinv[s0], w1 = dinv[s1], w2 = dinv[s2], w3 = dinv[s3];
            float w4 = dinv[s4], w5 = dinv[s5], w6 = dinv[s6], w7 = dinv[s7];
            acc.x += w0 * h0.x + w1 * h1.x + w2 * h2.x + w3 * h3.x
                   + w4 * h4.x + w5 * h5.x + w6 * h6.x + w7 * h7.x;
            acc.y += w0 * h0.y + w1 * h1.y + w2 * h2.y + w3 * h3.y
                   + w4 * h4.y + w5 * h5.y + w6 * h6.y + w7 * h7.y;
            acc.z += w0 * h0.z + w1 * h1.z + w2 * h2.z + w3 * h3.z
                   + w4 * h4.z + w5 * h5.z + w6 * h6.z + w7 * h7.z;
            acc.w += w0 * h0.w + w1 * h1.w + w2 * h2.w + w3 * h3.w
                   + w4 * h4.w + w5 * h5.w + w6 * h6.w + w7 * h7.w;
        }
        for (; e + 4 <= end; e += 4) {
            int s0 = r[e], s1 = r[e + 1], s2 = r[e + 2], s3 = r[e + 3];
            float4 h0 = x[(size_t)s0 * 4 + lane];
            float4 h1 = x[(size_t)s1 * 4 + lane];
            float4 h2 = x[(size_t)s2 * 4 + lane];
            float4 h3 = x[(size_t)s3 * 4 + lane];
            float w0 = dinv[s0], w1 = dinv[s1], w2 = dinv[s2], w3 = dinv[s3];
            acc.x += w0 * h0.x + w1 * h1.x + w2 * h2.x + w3 * h3.x;
            acc.y += w0 * h0.y + w1 * h1.y + w2 * h2.y + w3 * h3.y;
            acc.z += w0 * h0.z + w1 * h1.z + w2 * h2.z + w3 * h3.z;
            acc.w += w0 * h0.w + w1 * h1.w + w2 * h2.w + w3 * h3.w;
        }
        for (; e < end; e++) {
            int s = r[e];
            float w = dinv[s];
            float4 hs = x[(size_t)s * 4 + lane];
            acc.x += w * hs.x; acc.y += w * hs.y; acc.z += w * hs.z; acc.w += w * hs.w;
        }
        float sc = dv * inv_cnt;
        sagg[grp][lane * 4 + 0] = acc.x * sc;
        sagg[grp][lane * 4 + 1] = acc.y * sc;
        sagg[grp][lane * 4 + 2] = acc.z * sc;
        sagg[grp][lane * 4 + 3] = acc.w * sc;
    }
    __syncthreads();

    int vg = tid >> 2;
    int c0 = (tid & 3) * 16;
    int vout = blockIdx.x * 64 + vg;
    if (vout >= n) return;
    float o[16];
    #pragma unroll
    for (int jj = 0; jj < 16; jj++) o[jj] = sb[c0 + jj];
    #pragma unroll
    for (int k = 0; k < 16; k++) {
        float a = sagg[vg][k];
        #pragma unroll
        for (int jj = 0; jj < 16; jj++) o[jj] += a * sW[k * 64 + c0 + jj];
    }
    short8 p0, p1;
    #pragma unroll
    for (int jj = 0; jj < 8; jj++) p0[jj] = (short)f2bf(fmaxf(o[jj], 0.0f));
    #pragma unroll
    for (int jj = 0; jj < 8; jj++) p1[jj] = (short)f2bf(fmaxf(o[jj + 8], 0.0f));
    *(short8*)(h_out + (size_t)vout * 64 + c0) = p0;
    *(short8*)(h_out + (size_t)vout * 64 + c0 + 8) = p1;
}

// ---------------- bf16 ELL pre-aggregation (layer 2, d=64), unroll-8 --------

__global__ void k_agg_ell_bf16(const short8* __restrict__ h, short8* __restrict__ out,
                               const int* __restrict__ ell, const int* __restrict__ cnt,
                               const float* __restrict__ dinv, int n, int g_shift) {
    int g = 1 << g_shift;                        // lanes per node = d/8
    int grp = threadIdx.x >> g_shift;
    int lane = threadIdx.x & (g - 1);
    int gpb = blockDim.x >> g_shift;
    int v = blockIdx.x * gpb + grp;
    if (v >= n) return;
    float dv = dinv[v];
    int end = cnt[v];
    float inv_cnt = 1.0f / (float)(end + 1);
    const int* r = ell + ((size_t)v << 6);

    float acc[8];
    short8 hv = h[(size_t)v * g + lane];
    #pragma unroll
    for (int i = 0; i < 8; i++) acc[i] = dv * bf2f(hv[i]);   // dv factored out

    int e = 0;
    for (; e + 8 <= end; e += 8) {
        int s0 = r[e],     s1 = r[e + 1], s2 = r[e + 2], s3 = r[e + 3];
        int s4 = r[e + 4], s5 = r[e + 5], s6 = r[e + 6], s7 = r[e + 7];
        short8 h0 = h[(size_t)s0 * g + lane];
        short8 h1 = h[(size_t)s1 * g + lane];
        short8 h2 = h[(size_t)s2 * g + lane];
        short8 h3 = h[(size_t)s3 * g + lane];
        short8 h4 = h[(size_t)s4 * g + lane];
        short8 h5 = h[(size_t)s5 * g + lane];
        short8 h6 = h[(size_t)s6 * g + lane];
        short8 h7 = h[(size_t)s7 * g + lane];
        float w0 = dinv[s0], w1 = dinv[s1], w2 = dinv[s2], w3 = dinv[s3];
        float w4 = dinv[s4], w5 = dinv[s5], w6 = dinv[s6], w7 = dinv[s7];
        #pragma unroll
        for (int i = 0; i < 8; i++)
            acc[i] += w0 * bf2f(h0[i]) + w1 * bf2f(h1[i])
                    + w2 * bf2f(h2[i]) + w3 * bf2f(h3[i])
                    + w4 * bf2f(h4[i]) + w5 * bf2f(h5[i])
                    + w6 * bf2f(h6[i]) + w7 * bf2f(h7[i]);
    }
    for (; e + 4 <= end; e += 4) {
        int s0 = r[e], s1 = r[e + 1], s2 = r[e + 2], s3 = r[e + 3];
        short8 h0 = h[(size_t)s0 * g + lane];
        short8 h1 = h[(size_t)s1 * g + lane];
        short8 h2 = h[(size_t)s2 * g + lane];
        short8 h3 = h[(size_t)s3 * g + lane];
        float w0 = dinv[s0], w1 = dinv[s1], w2 = dinv[s2], w3 = dinv[s3];
        #pragma unroll
        for (int i = 0; i < 8; i++)
            acc[i] += w0 * bf2f(h0[i]) + w1 * bf2f(h1[i])
                    + w2 * bf2f(h2[i]) + w3 * bf2f(h3[i]);
    }
    for (; e < end; e++) {
        int s0 = r[e];
        float w0 = dinv[s0];
        short8 h0 = h[(size_t)s0 * g + lane];
        #pragma unroll
        for (int i = 0; i < 8; i++) acc[i] += w0 * bf2f(h0[i]);
    }
    float sc = dv * inv_cnt;
    short8 o;
    #pragma unroll
    for (int i = 0; i < 8; i++) o[i] = (short)f2bf(acc[i] * sc);
    out[(size_t)v * g + lane] = o;
}

// ---------------- XCD-sliced bf16 aggregation (layers 3/4) ------------------

__global__ __launch_bounds__(256) void k_agg_ell_sliced(
        const short8* __restrict__ h, short8* __restrict__ out,
        const int* __restrict__ ell, const int* __restrict__ cnt,
        const float* __restrict__ dinv, int n, int gfull_shift,
        int ns_shift, int tiles_per_sub) {
    int bid = blockIdx.x;
    int xcd = bid & 7;
    int t   = bid >> 3;
    if (t >= tiles_per_sub) return;
    int slice = xcd >> (3 - ns_shift);
    int sub   = xcd & ((8 >> ns_shift) - 1);

    int grp  = threadIdx.x >> 3;
    int lane = threadIdx.x & 7;
    int v = (sub * tiles_per_sub + t) * 32 + grp;
    if (v >= n) return;

    int fb = slice * 8 + lane;

    float dv = dinv[v];
    int end = cnt[v];
    float inv_cnt = 1.0f / (float)(end + 1);
    const int* r = ell + ((size_t)v << 6);

    float acc[8];
    short8 hv = h[((size_t)v << gfull_shift) + fb];
    #pragma unroll
    for (int i = 0; i < 8; i++) acc[i] = dv * bf2f(hv[i]);

    int e = 0;
    for (; e + 8 <= end; e += 8) {
        int s0 = r[e],     s1 = r[e + 1], s2 = r[e + 2], s3 = r[e + 3];
        int s4 = r[e + 4], s5 = r[e + 5], s6 = r[e + 6], s7 = r[e + 7];
        short8 h0 = h[((size_t)s0 << gfull_shift) + fb];
        short8 h1 = h[((size_t)s1 << gfull_shift) + fb];
        short8 h2 = h[((size_t)s2 << gfull_shift) + fb];
        short8 h3 = h[((size_t)s3 << gfull_shift) + fb];
        short8 h4 = h[((size_t)s4 << gfull_shift) + fb];
        short8 h5 = h[((size_t)s5 << gfull_shift) + fb];
        short8 h6 = h[((size_t)s6 << gfull_shift) + fb];
        short8 h7 = h[((size_t)s7 << gfull_shift) + fb];
        float w0 = dinv[s0], w1 = dinv[s1], w2 = dinv[s2], w3 = dinv[s3];
        float w4 = dinv[s4], w5 = dinv[s5], w6 = dinv[s6], w7 = dinv[s7];
        #pragma unroll
        for (int i = 0; i < 8; i++)
            acc[i] += w0 * bf2f(h0[i]) + w1 * bf2f(h1[i])
                    + w2 * bf2f(h2[i]) + w3 * bf2f(h3[i])
                    + w4 * bf2f(h4[i]) + w5 * bf2f(h5[i])
                    + w6 * bf2f(h6[i]) + w7 * bf2f(h7[i]);
    }
    for (; e + 4 <= end; e += 4) {
        int s0 = r[e], s1 = r[e + 1], s2 = r[e + 2], s3 = r[e + 3];
        short8 h0 = h[((size_t)s0 << gfull_shift) + fb];
        short8 h1 = h[((size_t)s1 << gfull_shift) + fb];
        short8 h2 = h[((size_t)s2 << gfull_shift) + fb];
        short8 h3 = h[((size_t)s3 << gfull_shift) + fb];
        float w0 = dinv[s0], w1 = dinv[s1], w2 = dinv[s2], w3 = dinv[s3];
        #pragma unroll
        for (int i = 0; i < 8; i++)
            acc[i] += w0 * bf2f(h0[i]) + w1 * bf2f(h1[i])
                    + w2 * bf2f(h2[i]) + w3 * bf2f(h3[i]);
    }
    for (; e < end; e++) {
        int s0 = r[e];
        float w0 = dinv[s0];
        short8 h0 = h[((size_t)s0 << gfull_shift) + fb];
        #pragma unroll
        for (int i = 0; i < 8; i++) acc[i] += w0 * bf2f(h0[i]);
    }
    float sc = dv * inv_cnt;
    short8 o;
    #pragma unroll
    for (int i = 0; i < 8; i++) o[i] = (short)f2bf(acc[i] * sc);
    out[((size_t)v << gfull_shift) + fb] = o;
}

// ---------------- MFMA GEMM: C_bf16[M,N] = relu(A[M,K] @ Wt[N,K]^T + bias) --
// M padded to 128 multiple (no M checks). Reg-prefetch of next K-tile.
// dotw != nullptr: instead of storing C, compute z[row] += dot(relu(row), dotw)
// via quad shfl-reduce + one float atomicAdd per (row, col-tile).

#define GBM 128
#define GBN 128
#define GBK 32
#define LDSS 40   // LDS row stride in elements (80B, 16B-aligned)

__global__ __launch_bounds__(256) void gemm_mfma(const ushort* __restrict__ A,
                                                 const ushort* __restrict__ Wt,
                                                 const float* __restrict__ bias,
                                                 ushort* __restrict__ C,
                                                 const float* __restrict__ dotw,
                                                 float* __restrict__ z,
                                                 int K, int N, int do_relu) {
    __shared__ ushort As[GBM * LDSS];
    __shared__ ushort Bs[GBN * LDSS];
    int tid = threadIdx.x;
    int wave = tid >> 6;
    int lane = tid & 63;
    int wr = wave >> 1, wc = wave & 1;
    int q = lane >> 4;          // quad 0..3
    int mr = lane & 15;
    int row0 = blockIdx.y * GBM;
    int col0 = blockIdx.x * GBN;

    int sr = tid >> 2;          // staging row 0..63 (and sr+64)
    int skoff = (tid & 3) * 8;  // staging k offset

    f32x4 acc[4][4];
    #pragma unroll
    for (int i = 0; i < 4; i++)
        #pragma unroll
        for (int j = 0; j < 4; j++) acc[i][j] = (f32x4){0.f, 0.f, 0.f, 0.f};

    const short8 zero8 = {0, 0, 0, 0, 0, 0, 0, 0};
    short8 va0, va1, vb0, vb1;
    int gn0 = col0 + sr, gn1 = col0 + sr + 64;

    {
        int gk = skoff;
        bool kin = gk < K;
        va0 = kin ? *(const short8*)(A + (size_t)(row0 + sr) * K + gk) : zero8;
        va1 = kin ? *(const short8*)(A + (size_t)(row0 + sr + 64) * K + gk) : zero8;
        vb0 = (kin && gn0 < N) ? *(const short8*)(Wt + (size_t)gn0 * K + gk) : zero8;
        vb1 = (kin && gn1 < N) ? *(const short8*)(Wt + (size_t)gn1 * K + gk) : zero8;
        *(short8*)(As + sr * LDSS + skoff) = va0;
        *(short8*)(As + (sr + 64) * LDSS + skoff) = va1;
        *(short8*)(Bs + sr * LDSS + skoff) = vb0;
        *(short8*)(Bs + (sr + 64) * LDSS + skoff) = vb1;
    }
    __syncthreads();

    for (int k0 = 0;;) {
        int k1 = k0 + GBK;
        bool more = (k1 < K);
        if (more) {                       // prefetch next tile into registers
            int gk = k1 + skoff;
            bool kin = gk < K;
            va0 = kin ? *(const short8*)(A + (size_t)(row0 + sr) * K + gk) : zero8;
            va1 = kin ? *(const short8*)(A + (size_t)(row0 + sr + 64) * K + gk) : zero8;
            vb0 = (kin && gn0 < N) ? *(const short8*)(Wt + (size_t)gn0 * K + gk) : zero8;
            vb1 = (kin && gn1 < N) ? *(const short8*)(Wt + (size_t)gn1 * K + gk) : zero8;
        }
        short8 afr[4], bfr[4];
        #pragma unroll
        for (int i = 0; i < 4; i++)
            afr[i] = *(const short8*)(As + (wr * 64 + i * 16 + mr) * LDSS + q * 8);
        #pragma unroll
        for (int j = 0; j < 4; j++)
            bfr[j] = *(const short8*)(Bs + (wc * 64 + j * 16 + mr) * LDSS + q * 8);
        #pragma unroll
        for (int i = 0; i < 4; i++)
            #pragma unroll
            for (int j = 0; j < 4; j++)
                acc[i][j] = __builtin_amdgcn_mfma_f32_16x16x32_bf16(afr[i], bfr[j],
                                                                    acc[i][j], 0, 0, 0);
        if (!more) break;
        __syncthreads();
        *(short8*)(As + sr * LDSS + skoff) = va0;
        *(short8*)(As + (sr + 64) * LDSS + skoff) = va1;
        *(short8*)(Bs + sr * LDSS + skoff) = vb0;
        *(short8*)(Bs + (sr + 64) * LDSS + skoff) = vb1;
        __syncthreads();
        k0 = k1;
    }

    if (dotw) {
        // fused final-layer dot: z[row] += sum_col relu(acc+bias)*dotw[col]
        float bj[4], wj[4];
        #pragma unroll
        for (int j = 0; j < 4; j++) {
            int col = col0 + wc * 64 + j * 16 + mr;
            bj[j] = bias[col];
            wj[j] = dotw[col];
        }
        #pragma unroll
        for (int i = 0; i < 4; i++) {
            #pragma unroll
            for (int r = 0; r < 4; r++) {
                float p = 0.0f;
                #pragma unroll
                for (int j = 0; j < 4; j++)
                    p += fmaxf(acc[i][j][r] + bj[j], 0.0f) * wj[j];
                #pragma unroll
                for (int off = 1; off < 16; off <<= 1)
                    p += __shfl_xor(p, off, 64);   // reduce over mr within quad
                if (mr == 0)
                    atomicAdd(&z[row0 + wr * 64 + i * 16 + q * 4 + r], p);
            }
        }
        return;
    }

    // epilogue: C/D layout col=lane&15, row=q*4+reg; emit bf16 (no M check)
    #pragma unroll
    for (int j = 0; j < 4; j++) {
        int col = col0 + wc * 64 + j * 16 + mr;
        if (col >= N) continue;
        float bj = bias[col];
        #pragma unroll
        for (int i = 0; i < 4; i++) {
            int rbase = row0 + wr * 64 + i * 16 + q * 4;
            #pragma unroll
            for (int r = 0; r < 4; r++) {
                float v = acc[i][j][r] + bj;
                if (do_relu) v = fmaxf(v, 0.0f);
                C[(size_t)(rbase + r) * N + col] = f2bf(v);
            }
        }
    }
}

// ---------------- final: add-aggregate z + bias + sigmoid ----------------

__global__ void k_agg_final(const float* __restrict__ h, float* __restrict__ out,
                            const int* __restrict__ ell, const int* __restrict__ cnt,
                            const float* __restrict__ dinv, const float* __restrict__ b5,
                            int n) {
    int v = blockIdx.x * blockDim.x + threadIdx.x;
    if (v >= n) return;
    float dv = dinv[v];
    float acc = dv * h[v];
    int end = cnt[v];
    const int* r = ell + ((size_t)v << 6);
    for (int e = 0; e < end; e++) {
        int s = r[e];
        acc += dinv[s] * h[s];
    }
    float rr = dv * acc + b5[0];
    out[v] = 1.0f / (1.0f + expf(-rr));
}

// ---------------- launch ----------------

extern "C" void kernel_launch(void* const* d_in, const int* in_sizes, int n_in,
                              void* d_out, int out_size, void* d_ws, size_t ws_size,
                              hipStream_t stream) {
    const float* x   = (const float*)d_in[0];
    const int*   ei  = (const int*)d_in[1];
    const float* W[5] = {(const float*)d_in[2], (const float*)d_in[4], (const float*)d_in[6],
                         (const float*)d_in[8], (const float*)d_in[10]};
    const float* b[5] = {(const float*)d_in[3], (const float*)d_in[5], (const float*)d_in[7],
                         (const float*)d_in[9], (const float*)d_in[11]};
    const int n = in_sizes[0] / 16;
    const int E = in_sizes[1] / 2;
    const int dims[6] = {16, 64, 128, 256, 512, 1};

    const int* e_row = ei;          // src
    const int* e_col = ei + E;      // dst

    // workspace layout
    float* bufA_f = (float*)d_ws;                     // n*512 floats region
    float* bufB_f = bufA_f + (size_t)n * 512;         // n*512 floats region
    ushort* bufA  = (ushort*)bufA_f;                  // h (GEMM out, bf16)
    ushort* bufB  = (ushort*)bufB_f;                  // agg out (bf16)
    int*   cnt    = (int*)(bufB_f + (size_t)n * 512); // n
    float* dinv   = (float*)(cnt + n);                // n
    int*   ell    = (int*)(dinv + n);                 // n * ELLW
    ushort* wt2   = (ushort*)(ell + (size_t)n * ELLW);
    ushort* wt3   = wt2 + 64 * 128;
    ushort* wt4   = wt3 + 128 * 256;
    float* z      = (float*)(wt4 + 256 * 512);        // Mpad floats
    ushort* wts[4] = {nullptr, wt2, wt3, wt4};

    const int Mpad = (n + GBM - 1) / GBM * GBM;       // 20096
    const int ntiles32 = (n + 31) / 32;               // 625

    // ---- prep ----
    k_zero<<<(n + 255) / 256, 256, 0, stream>>>(cnt, n);
    k_fill_ell<<<(E + 255) / 256, 256, 0, stream>>>(e_row, e_col, cnt, ell, E,
                                                    W[1], W[2], W[3], wt2, wt3, wt4);
    k_deg<<<(Mpad + 255) / 256, 256, 0, stream>>>(cnt, dinv, z, n, Mpad);

    // ---- layer 1: fused agg(d=16) + 16x64 GEMM + relu -> bf16 h ----
    k_l1_fused<<<(n + 63) / 64, 256, 0, stream>>>(
        (const float4*)x, bufA, ell, cnt, dinv, W[0], b[0], n);

    // ---- layer 2 ----
    {
        int K = 64, Nd = 128;
        k_agg_ell_bf16<<<(n + 31) / 32, 256, 0, stream>>>(
            (const short8*)bufA, (short8*)bufB, ell, cnt, dinv, n, 3);
        dim3 ggrid(Nd / GBN, Mpad / GBM);
        gemm_mfma<<<ggrid, 256, 0, stream>>>(bufB, wts[1], b[1], bufA,
                                             nullptr, nullptr, K, Nd, 1);
    }

    // ---- layer 3 ----
    {
        int K = 128, Nd = 256;
        int ns_shift = 1, xps = 8 >> ns_shift;
        int tps = (ntiles32 + xps - 1) / xps;
        k_agg_ell_sliced<<<8 * tps, 256, 0, stream>>>(
            (const short8*)bufA, (short8*)bufB, ell, cnt, dinv, n, 4, ns_shift, tps);
        dim3 ggrid(Nd / GBN, Mpad / GBM);
        gemm_mfma<<<ggrid, 256, 0, stream>>>(bufB, wts[2], b[2], bufA,
                                             nullptr, nullptr, K, Nd, 1);
    }

    // ---- layer 4 + fused layer-5 dot ----
    {
        int K = 256, Nd = 512;
        int ns_shift = 2, xps = 8 >> ns_shift;
        int tps = (ntiles32 + xps - 1) / xps;
        k_agg_ell_sliced<<<8 * tps, 256, 0, stream>>>(
            (const short8*)bufA, (short8*)bufB, ell, cnt, dinv, n, 5, ns_shift, tps);
        dim3 ggrid(Nd / GBN, Mpad / GBM);
        gemm_mfma<<<ggrid, 256, 0, stream>>>(bufB, wts[3], b[3], nullptr,
                                             W[4], z, K, Nd, 1);
    }

    // ---- layer 5: add-aggregate + sigmoid ----
    k_agg_final<<<(n + 255) / 256, 256, 0, stream>>>(z, (float*)d_out, ell, cnt,
                                                     dinv, b[4], n);
}

// Round 6
// 207.721 us; speedup vs baseline: 5.2657x; 1.0048x over previous
//
#include <hip/hip_runtime.h>
#include <hip/hip_bf16.h>
#include <math.h>

// GCN 5-layer: dims 16->64->128->256->512->1, N=20000, E=320000.
// Round 15: r14 base, 10 -> 9 dispatches. k_deg deleted (dinv = rsqrtf(cnt+1)
// inlined at every use -- bit-identical values; z-zero folded into k_zero).
// Layers 3/4 revert to the simple agg kernel (XCD-sliced variant measured
// null in r12; simple path reads ell/cnt once). GEMM staging bounds checks
// dropped (K,N always exact tile multiples here).

#define N_NODES 20000
#define N_EDGES 320000
#define ELLW 64   // P(in-deg >= 48) ~ 1e-10 for Poisson(16)

typedef __attribute__((ext_vector_type(8))) short short8;
typedef __attribute__((ext_vector_type(4))) float f32x4;

__device__ inline ushort f2bf(float f) {
    __hip_bfloat16 h = __float2bfloat16(f);   // RNE
    return *(ushort*)&h;
}

__device__ inline float bf2f(short s) {
    union { unsigned int u; float f; } c;
    c.u = ((unsigned int)(unsigned short)s) << 16;
    return c.f;
}

__device__ __forceinline__ float dinv_of(const int* __restrict__ cnt, int v) {
    return rsqrtf((float)(cnt[v] + 1));       // in-degree + self-loop
}

// ---------------- prep: zero cnt + z ----------------

__global__ void k_zero(int* __restrict__ cnt, float* __restrict__ z, int n, int mpad) {
    int i = blockIdx.x * blockDim.x + threadIdx.x;
    if (i < n) cnt[i] = 0;
    if (i < mpad) z[i] = 0.0f;
}

// ---------------- ELL build + weight transposes (ride the same grid) --------
// transpose segments (N*K): 8192 | 32768 | 131072 -> total 172032 < E

__global__ void k_fill_ell(const int* __restrict__ row, const int* __restrict__ col,
                           int* __restrict__ cnt, int* __restrict__ ell, int E,
                           const float* __restrict__ W2, const float* __restrict__ W3,
                           const float* __restrict__ W4,
                           ushort* __restrict__ T2, ushort* __restrict__ T3,
                           ushort* __restrict__ T4) {
    int e = blockIdx.x * blockDim.x + threadIdx.x;
    if (e < 172032) {
        const float* W; ushort* T; int K, N, j;
        if (e < 8192)        { W = W2; T = T2; K = 64;  N = 128; j = e; }
        else if (e < 40960)  { W = W3; T = T3; K = 128; N = 256; j = e - 8192; }
        else                 { W = W4; T = T4; K = 256; N = 512; j = e - 40960; }
        int nn = j / K, kk = j - nn * K;
        T[(size_t)nn * K + kk] = f2bf(W[(size_t)kk * N + nn]);
    }
    if (e >= E) return;
    int s = row[e], d = col[e];
    int pos = atomicAdd(&cnt[d], 1);
    ell[((size_t)d << 6) + pos] = s;
}

// ---------------- layer 1 fused: agg(d=16, fp32) + GEMM 16x64 + relu --------
// 256 threads = 64 nodes/block (4 lanes/node for agg, 4 col-groups/node GEMM).

__global__ __launch_bounds__(256) void k_l1_fused(const float4* __restrict__ x,
                                                  ushort* __restrict__ h_out,
                                                  const int* __restrict__ ell,
                                                  const int* __restrict__ cnt,
                                                  const float* __restrict__ W,
                                                  const float* __restrict__ b, int n) {
    __shared__ float sW[16 * 64];
    __shared__ float sb[64];
    __shared__ float sagg[64][17];    // padded: avoid bank conflicts
    int tid = threadIdx.x;
    #pragma unroll
    for (int i = tid; i < 1024; i += 256) sW[i] = W[i];
    if (tid < 64) sb[tid] = b[tid];

    int grp = tid >> 2;               // node within block
    int lane = tid & 3;               // float4 lane (4 feats each)
    int v = blockIdx.x * 64 + grp;
    if (v < n) {
        float dv = dinv_of(cnt, v);
        int end = cnt[v];
        float inv_cnt = 1.0f / (float)(end + 1);
        const int* r = ell + ((size_t)v << 6);
        float4 hv = x[(size_t)v * 4 + lane];
        float4 acc = make_float4(dv * hv.x, dv * hv.y, dv * hv.z, dv * hv.w);
        int e = 0;
        for (; e + 8 <= end; e += 8) {
            int s0 = r[e],     s1 = r[e + 1], s2 = r[e + 2], s3 = r[e + 3];
            int s4 = r[e + 4], s5 = r[e + 5], s6 = r[e + 6], s7 = r[e + 7];
            float4 h0 = x[(size_t)s0 * 4 + lane];
            float4 h1 = x[(size_t)s1 * 4 + lane];
            float4 h2 = x[(size_t)s2 * 4 + lane];
            float4 h3 = x[(size_t)s3 * 4 + lane];
            float4 h4 = x[(size_t)s4 * 4 + lane];
            float4 h5 = x[(size_t)s5 * 4 + lane];
            float4 h6 = x[(size_t)s6 * 4 + lane];
            float4 h7 = x[(size_t)s7 * 4 + lane];
            float w0 = dinv_of(cnt, s0), w1 = dinv_of(cnt, s1);
            float w2 = dinv_of(cnt, s2), w3 = dinv_of(cnt, s3);
            float w4 = dinv_of(cnt, s4), w5 = dinv_of(cnt, s5);
            float w6 = dinv_of(cnt, s6), w7 = dinv_of(cnt, s7);
            acc.x += w0 * h0.x + w1 * h1.x + w2 * h2.x + w3 * h3.x
                   + w4 * h4.x + w5 * h5.x + w6 * h6.x + w7 * h7.x;
            acc.y += w0 * h0.y + w1 * h1.y + w2 * h2.y + w3 * h3.y
                   + w4 * h4.y + w5 * h5.y + w6 * h6.y + w7 * h7.y;
            acc.z += w0 * h0.z + w1 * h1.z + w2 * h2.z + w3 * h3.z
                   + w4 * h4.z + w5 * h5.z + w6 * h6.z + w7 * h7.z;
            acc.w += w0 * h0.w + w1 * h1.w + w2 * h2.w + w3 * h3.w
                   + w4 * h4.w + w5 * h5.w + w6 * h6.w + w7 * h7.w;
        }
        for (; e + 4 <= end; e += 4) {
            int s0 = r[e], s1 = r[e + 1], s2 = r[e + 2], s3 = r[e + 3];
            float4 h0 = x[(size_t)s0 * 4 + lane];
            float4 h1 = x[(size_t)s1 * 4 + lane];
            float4 h2 = x[(size_t)s2 * 4 + lane];
            float4 h3 = x[(size_t)s3 * 4 + lane];
            float w0 = dinv_of(cnt, s0), w1 = dinv_of(cnt, s1);
            float w2 = dinv_of(cnt, s2), w3 = dinv_of(cnt, s3);
            acc.x += w0 * h0.x + w1 * h1.x + w2 * h2.x + w3 * h3.x;
            acc.y += w0 * h0.y + w1 * h1.y + w2 * h2.y + w3 * h3.y;
            acc.z += w0 * h0.z + w1 * h1.z + w2 * h2.z + w3 * h3.z;
            acc.w += w0 * h0.w + w1 * h1.w + w2 * h2.w + w3 * h3.w;
        }
        for (; e < end; e++) {
            int s = r[e];
            float w = dinv_of(cnt, s);
            float4 hs = x[(size_t)s * 4 + lane];
            acc.x += w * hs.x; acc.y += w * hs.y; acc.z += w * hs.z; acc.w += w * hs.w;
        }
        float sc = dv * inv_cnt;
        sagg[grp][lane * 4 + 0] = acc.x * sc;
        sagg[grp][lane * 4 + 1] = acc.y * sc;
        sagg[grp][lane * 4 + 2] = acc.z * sc;
        sagg[grp][lane * 4 + 3] = acc.w * sc;
    }
    __syncthreads();

    int vg = tid >> 2;
    int c0 = (tid & 3) * 16;
    int vout = blockIdx.x * 64 + vg;
    if (vout >= n) return;
    float o[16];
    #pragma unroll
    for (int jj = 0; jj < 16; jj++) o[jj] = sb[c0 + jj];
    #pragma unroll
    for (int k = 0; k < 16; k++) {
        float a = sagg[vg][k];
        #pragma unroll
        for (int jj = 0; jj < 16; jj++) o[jj] += a * sW[k * 64 + c0 + jj];
    }
    short8 p0, p1;
    #pragma unroll
    for (int jj = 0; jj < 8; jj++) p0[jj] = (short)f2bf(fmaxf(o[jj], 0.0f));
    #pragma unroll
    for (int jj = 0; jj < 8; jj++) p1[jj] = (short)f2bf(fmaxf(o[jj + 8], 0.0f));
    *(short8*)(h_out + (size_t)vout * 64 + c0) = p0;
    *(short8*)(h_out + (size_t)vout * 64 + c0 + 8) = p1;
}

// ---------------- bf16 ELL pre-aggregation (layers 2..4), unroll-8 ----------

__global__ void k_agg_ell_bf16(const short8* __restrict__ h, short8* __restrict__ out,
                               const int* __restrict__ ell, const int* __restrict__ cnt,
                               int n, int g_shift) {
    int g = 1 << g_shift;                        // lanes per node = d/8
    int grp = threadIdx.x >> g_shift;
    int lane = threadIdx.x & (g - 1);
    int gpb = blockDim.x >> g_shift;
    int v = blockIdx.x * gpb + grp;
    if (v >= n) return;
    float dv = dinv_of(cnt, v);
    int end = cnt[v];
    float inv_cnt = 1.0f / (float)(end + 1);
    const int* r = ell + ((size_t)v << 6);

    float acc[8];
    short8 hv = h[(size_t)v * g + lane];
    #pragma unroll
    for (int i = 0; i < 8; i++) acc[i] = dv * bf2f(hv[i]);   // dv factored out

    int e = 0;
    for (; e + 8 <= end; e += 8) {
        int s0 = r[e],     s1 = r[e + 1], s2 = r[e + 2], s3 = r[e + 3];
        int s4 = r[e + 4], s5 = r[e + 5], s6 = r[e + 6], s7 = r[e + 7];
        short8 h0 = h[(size_t)s0 * g + lane];
        short8 h1 = h[(size_t)s1 * g + lane];
        short8 h2 = h[(size_t)s2 * g + lane];
        short8 h3 = h[(size_t)s3 * g + lane];
        short8 h4 = h[(size_t)s4 * g + lane];
        short8 h5 = h[(size_t)s5 * g + lane];
        short8 h6 = h[(size_t)s6 * g + lane];
        short8 h7 = h[(size_t)s7 * g + lane];
        float w0 = dinv_of(cnt, s0), w1 = dinv_of(cnt, s1);
        float w2 = dinv_of(cnt, s2), w3 = dinv_of(cnt, s3);
        float w4 = dinv_of(cnt, s4), w5 = dinv_of(cnt, s5);
        float w6 = dinv_of(cnt, s6), w7 = dinv_of(cnt, s7);
        #pragma unroll
        for (int i = 0; i < 8; i++)
            acc[i] += w0 * bf2f(h0[i]) + w1 * bf2f(h1[i])
                    + w2 * bf2f(h2[i]) + w3 * bf2f(h3[i])
                    + w4 * bf2f(h4[i]) + w5 * bf2f(h5[i])
                    + w6 * bf2f(h6[i]) + w7 * bf2f(h7[i]);
    }
    for (; e + 4 <= end; e += 4) {
        int s0 = r[e], s1 = r[e + 1], s2 = r[e + 2], s3 = r[e + 3];
        short8 h0 = h[(size_t)s0 * g + lane];
        short8 h1 = h[(size_t)s1 * g + lane];
        short8 h2 = h[(size_t)s2 * g + lane];
        short8 h3 = h[(size_t)s3 * g + lane];
        float w0 = dinv_of(cnt, s0), w1 = dinv_of(cnt, s1);
        float w2 = dinv_of(cnt, s2), w3 = dinv_of(cnt, s3);
        #pragma unroll
        for (int i = 0; i < 8; i++)
            acc[i] += w0 * bf2f(h0[i]) + w1 * bf2f(h1[i])
                    + w2 * bf2f(h2[i]) + w3 * bf2f(h3[i]);
    }
    for (; e < end; e++) {
        int s0 = r[e];
        float w0 = dinv_of(cnt, s0);
        short8 h0 = h[(size_t)s0 * g + lane];
        #pragma unroll
        for (int i = 0; i < 8; i++) acc[i] += w0 * bf2f(h0[i]);
    }
    float sc = dv * inv_cnt;
    short8 o;
    #pragma unroll
    for (int i = 0; i < 8; i++) o[i] = (short)f2bf(acc[i] * sc);
    out[(size_t)v * g + lane] = o;
}

// ---------------- MFMA GEMM: C_bf16[M,N] = relu(A[M,K] @ Wt[N,K]^T + bias) --
// M padded to 128 multiple, K/N exact multiples -> no bounds checks at all.
// Reg-prefetch of next K-tile. dotw != nullptr: fused final-layer dot into z.

#define GBM 128
#define GBN 128
#define GBK 32
#define LDSS 40   // LDS row stride in elements (80B, 16B-aligned)

__global__ __launch_bounds__(256) void gemm_mfma(const ushort* __restrict__ A,
                                                 const ushort* __restrict__ Wt,
                                                 const float* __restrict__ bias,
                                                 ushort* __restrict__ C,
                                                 const float* __restrict__ dotw,
                                                 float* __restrict__ z,
                                                 int K, int N, int do_relu) {
    __shared__ ushort As[GBM * LDSS];
    __shared__ ushort Bs[GBN * LDSS];
    int tid = threadIdx.x;
    int wave = tid >> 6;
    int lane = tid & 63;
    int wr = wave >> 1, wc = wave & 1;
    int q = lane >> 4;          // quad 0..3
    int mr = lane & 15;
    int row0 = blockIdx.y * GBM;
    int col0 = blockIdx.x * GBN;

    int sr = tid >> 2;          // staging row 0..63 (and sr+64)
    int skoff = (tid & 3) * 8;  // staging k offset

    f32x4 acc[4][4];
    #pragma unroll
    for (int i = 0; i < 4; i++)
        #pragma unroll
        for (int j = 0; j < 4; j++) acc[i][j] = (f32x4){0.f, 0.f, 0.f, 0.f};

    short8 va0, va1, vb0, vb1;
    int gn0 = col0 + sr, gn1 = col0 + sr + 64;

    {
        va0 = *(const short8*)(A + (size_t)(row0 + sr) * K + skoff);
        va1 = *(const short8*)(A + (size_t)(row0 + sr + 64) * K + skoff);
        vb0 = *(const short8*)(Wt + (size_t)gn0 * K + skoff);
        vb1 = *(const short8*)(Wt + (size_t)gn1 * K + skoff);
        *(short8*)(As + sr * LDSS + skoff) = va0;
        *(short8*)(As + (sr + 64) * LDSS + skoff) = va1;
        *(short8*)(Bs + sr * LDSS + skoff) = vb0;
        *(short8*)(Bs + (sr + 64) * LDSS + skoff) = vb1;
    }
    __syncthreads();

    for (int k0 = 0;;) {
        int k1 = k0 + GBK;
        bool more = (k1 < K);
        if (more) {                       // prefetch next tile into registers
            int gk = k1 + skoff;
            va0 = *(const short8*)(A + (size_t)(row0 + sr) * K + gk);
            va1 = *(const short8*)(A + (size_t)(row0 + sr + 64) * K + gk);
            vb0 = *(const short8*)(Wt + (size_t)gn0 * K + gk);
            vb1 = *(const short8*)(Wt + (size_t)gn1 * K + gk);
        }
        short8 afr[4], bfr[4];
        #pragma unroll
        for (int i = 0; i < 4; i++)
            afr[i] = *(const short8*)(As + (wr * 64 + i * 16 + mr) * LDSS + q * 8);
        #pragma unroll
        for (int j = 0; j < 4; j++)
            bfr[j] = *(const short8*)(Bs + (wc * 64 + j * 16 + mr) * LDSS + q * 8);
        #pragma unroll
        for (int i = 0; i < 4; i++)
            #pragma unroll
            for (int j = 0; j < 4; j++)
                acc[i][j] = __builtin_amdgcn_mfma_f32_16x16x32_bf16(afr[i], bfr[j],
                                                                    acc[i][j], 0, 0, 0);
        if (!more) break;
        __syncthreads();
        *(short8*)(As + sr * LDSS + skoff) = va0;
        *(short8*)(As + (sr + 64) * LDSS + skoff) = va1;
        *(short8*)(Bs + sr * LDSS + skoff) = vb0;
        *(short8*)(Bs + (sr + 64) * LDSS + skoff) = vb1;
        __syncthreads();
        k0 = k1;
    }

    if (dotw) {
        // fused final-layer dot: z[row] += sum_col relu(acc+bias)*dotw[col]
        float bj[4], wj[4];
        #pragma unroll
        for (int j = 0; j < 4; j++) {
            int col = col0 + wc * 64 + j * 16 + mr;
            bj[j] = bias[col];
            wj[j] = dotw[col];
        }
        #pragma unroll
        for (int i = 0; i < 4; i++) {
            #pragma unroll
            for (int r = 0; r < 4; r++) {
                float p = 0.0f;
                #pragma unroll
                for (int j = 0; j < 4; j++)
                    p += fmaxf(acc[i][j][r] + bj[j], 0.0f) * wj[j];
                #pragma unroll
                for (int off = 1; off < 16; off <<= 1)
                    p += __shfl_xor(p, off, 64);   // reduce over mr within quad
                if (mr == 0)
                    atomicAdd(&z[row0 + wr * 64 + i * 16 + q * 4 + r], p);
            }
        }
        return;
    }

    // epilogue: C/D layout col=lane&15, row=q*4+reg; emit bf16
    #pragma unroll
    for (int j = 0; j < 4; j++) {
        int col = col0 + wc * 64 + j * 16 + mr;
        float bj = bias[col];
        #pragma unroll
        for (int i = 0; i < 4; i++) {
            int rbase = row0 + wr * 64 + i * 16 + q * 4;
            #pragma unroll
            for (int r = 0; r < 4; r++) {
                float v = acc[i][j][r] + bj;
                if (do_relu) v = fmaxf(v, 0.0f);
                C[(size_t)(rbase + r) * N + col] = f2bf(v);
            }
        }
    }
}

// ---------------- final: add-aggregate z + bias + sigmoid ----------------

__global__ void k_agg_final(const float* __restrict__ h, float* __restrict__ out,
                            const int* __restrict__ ell, const int* __restrict__ cnt,
                            const float* __restrict__ b5, int n) {
    int v = blockIdx.x * blockDim.x + threadIdx.x;
    if (v >= n) return;
    float dv = dinv_of(cnt, v);
    float acc = dv * h[v];
    int end = cnt[v];
    const int* r = ell + ((size_t)v << 6);
    for (int e = 0; e < end; e++) {
        int s = r[e];
        acc += dinv_of(cnt, s) * h[s];
    }
    float rr = dv * acc + b5[0];
    out[v] = 1.0f / (1.0f + expf(-rr));
}

// ---------------- launch ----------------

extern "C" void kernel_launch(void* const* d_in, const int* in_sizes, int n_in,
                              void* d_out, int out_size, void* d_ws, size_t ws_size,
                              hipStream_t stream) {
    const float* x   = (const float*)d_in[0];
    const int*   ei  = (const int*)d_in[1];
    const float* W[5] = {(const float*)d_in[2], (const float*)d_in[4], (const float*)d_in[6],
                         (const float*)d_in[8], (const float*)d_in[10]};
    const float* b[5] = {(const float*)d_in[3], (const float*)d_in[5], (const float*)d_in[7],
                         (const float*)d_in[9], (const float*)d_in[11]};
    const int n = in_sizes[0] / 16;
    const int E = in_sizes[1] / 2;

    const int* e_row = ei;          // src
    const int* e_col = ei + E;      // dst

    // workspace layout
    float* bufA_f = (float*)d_ws;                     // n*512 floats region
    float* bufB_f = bufA_f + (size_t)n * 512;         // n*512 floats region
    ushort* bufA  = (ushort*)bufA_f;                  // h (GEMM out, bf16)
    ushort* bufB  = (ushort*)bufB_f;                  // agg out (bf16)
    int*   cnt    = (int*)(bufB_f + (size_t)n * 512); // n
    int*   ell    = cnt + n;                          // n * ELLW
    ushort* wt2   = (ushort*)(ell + (size_t)n * ELLW);
    ushort* wt3   = wt2 + 64 * 128;
    ushort* wt4   = wt3 + 128 * 256;
    float* z      = (float*)(wt4 + 256 * 512);        // Mpad floats

    const int Mpad = (n + GBM - 1) / GBM * GBM;       // 20096

    // ---- prep ----
    k_zero<<<(Mpad + 255) / 256, 256, 0, stream>>>(cnt, z, n, Mpad);
    k_fill_ell<<<(E + 255) / 256, 256, 0, stream>>>(e_row, e_col, cnt, ell, E,
                                                    W[1], W[2], W[3], wt2, wt3, wt4);

    // ---- layer 1: fused agg(d=16) + 16x64 GEMM + relu -> bf16 h ----
    k_l1_fused<<<(n + 63) / 64, 256, 0, stream>>>(
        (const float4*)x, bufA, ell, cnt, W[0], b[0], n);

    // ---- layer 2 ----
    k_agg_ell_bf16<<<(n + 31) / 32, 256, 0, stream>>>(
        (const short8*)bufA, (short8*)bufB, ell, cnt, n, 3);
    {
        dim3 ggrid(128 / GBN, Mpad / GBM);
        gemm_mfma<<<ggrid, 256, 0, stream>>>(bufB, wt2, b[1], bufA,
                                             nullptr, nullptr, 64, 128, 1);
    }

    // ---- layer 3 ----
    k_agg_ell_bf16<<<(n + 15) / 16, 256, 0, stream>>>(
        (const short8*)bufA, (short8*)bufB, ell, cnt, n, 4);
    {
        dim3 ggrid(256 / GBN, Mpad / GBM);
        gemm_mfma<<<ggrid, 256, 0, stream>>>(bufB, wt3, b[2], bufA,
                                             nullptr, nullptr, 128, 256, 1);
    }

    // ---- layer 4 + fused layer-5 dot ----
    k_agg_ell_bf16<<<(n + 7) / 8, 256, 0, stream>>>(
        (const short8*)bufA, (short8*)bufB, ell, cnt, n, 5);
    {
        dim3 ggrid(512 / GBN, Mpad / GBM);
        gemm_mfma<<<ggrid, 256, 0, stream>>>(bufB, wt4, b[3], nullptr,
                                             W[4], z, 256, 512, 1);
    }

    // ---- layer 5: add-aggregate + sigmoid ----
    k_agg_final<<<(n + 255) / 256, 256, 0, stream>>>(z, (float*)d_out, ell, cnt,
                                                     b[4], n);
}

// Round 7
// 205.843 us; speedup vs baseline: 5.3137x; 1.0091x over previous
//
#include <hip/hip_runtime.h>
#include <hip/hip_bf16.h>
#include <math.h>

// GCN 5-layer: dims 16->64->128->256->512->1, N=20000, E=320000.
// Round 16: r15 base + precomputed per-edge aggregation weights.
// w_full[e] = dinv_s * dv * inv_cnt is layer-independent; lane 0 of each node
// group in k_l1_fused (which already walks every edge) stores it to ellw[].
// Layers 2-4 aggs then: selfw = inv_cnt^2 (dv^2 == inv_cnt, so NO rsqrt at
// all), weights via 2x float4 broadcast loads per 8 edges (was 8 broadcast
// loads + 8 rsqrts), and no output rescale. Final layer keeps on-the-fly
// dinv (add-aggregation, different weights, no lane redundancy).

#define N_NODES 20000
#define N_EDGES 320000
#define ELLW 64   // P(in-deg >= 48) ~ 1e-10 for Poisson(16)

typedef __attribute__((ext_vector_type(8))) short short8;
typedef __attribute__((ext_vector_type(4))) float f32x4;

__device__ inline ushort f2bf(float f) {
    __hip_bfloat16 h = __float2bfloat16(f);   // RNE
    return *(ushort*)&h;
}

__device__ inline float bf2f(short s) {
    union { unsigned int u; float f; } c;
    c.u = ((unsigned int)(unsigned short)s) << 16;
    return c.f;
}

__device__ __forceinline__ float dinv_of(const int* __restrict__ cnt, int v) {
    return rsqrtf((float)(cnt[v] + 1));       // in-degree + self-loop
}

// ---------------- prep: zero cnt + z ----------------

__global__ void k_zero(int* __restrict__ cnt, float* __restrict__ z, int n, int mpad) {
    int i = blockIdx.x * blockDim.x + threadIdx.x;
    if (i < n) cnt[i] = 0;
    if (i < mpad) z[i] = 0.0f;
}

// ---------------- ELL build + weight transposes (ride the same grid) --------
// transpose segments (N*K): 8192 | 32768 | 131072 -> total 172032 < E

__global__ void k_fill_ell(const int* __restrict__ row, const int* __restrict__ col,
                           int* __restrict__ cnt, int* __restrict__ ell, int E,
                           const float* __restrict__ W2, const float* __restrict__ W3,
                           const float* __restrict__ W4,
                           ushort* __restrict__ T2, ushort* __restrict__ T3,
                           ushort* __restrict__ T4) {
    int e = blockIdx.x * blockDim.x + threadIdx.x;
    if (e < 172032) {
        const float* W; ushort* T; int K, N, j;
        if (e < 8192)        { W = W2; T = T2; K = 64;  N = 128; j = e; }
        else if (e < 40960)  { W = W3; T = T3; K = 128; N = 256; j = e - 8192; }
        else                 { W = W4; T = T4; K = 256; N = 512; j = e - 40960; }
        int nn = j / K, kk = j - nn * K;
        T[(size_t)nn * K + kk] = f2bf(W[(size_t)kk * N + nn]);
    }
    if (e >= E) return;
    int s = row[e], d = col[e];
    int pos = atomicAdd(&cnt[d], 1);
    ell[((size_t)d << 6) + pos] = s;
}

// ---------------- layer 1 fused: agg(d=16, fp32) + GEMM 16x64 + relu --------
// 256 threads = 64 nodes/block. Lane 0 of each node group also stores the
// layer-independent full edge weights w_full = dinv_s * dv * inv_cnt.

__global__ __launch_bounds__(256) void k_l1_fused(const float4* __restrict__ x,
                                                  ushort* __restrict__ h_out,
                                                  const int* __restrict__ ell,
                                                  const int* __restrict__ cnt,
                                                  float* __restrict__ ellw,
                                                  const float* __restrict__ W,
                                                  const float* __restrict__ b, int n) {
    __shared__ float sW[16 * 64];
    __shared__ float sb[64];
    __shared__ float sagg[64][17];    // padded: avoid bank conflicts
    int tid = threadIdx.x;
    #pragma unroll
    for (int i = tid; i < 1024; i += 256) sW[i] = W[i];
    if (tid < 64) sb[tid] = b[tid];

    int grp = tid >> 2;               // node within block
    int lane = tid & 3;               // float4 lane (4 feats each)
    int v = blockIdx.x * 64 + grp;
    if (v < n) {
        float dv = dinv_of(cnt, v);
        int end = cnt[v];
        float inv_cnt = 1.0f / (float)(end + 1);
        float sc = dv * inv_cnt;
        const int* r = ell + ((size_t)v << 6);
        float* wrow = ellw + ((size_t)v << 6);
        float4 hv = x[(size_t)v * 4 + lane];
        float4 acc = make_float4(dv * hv.x, dv * hv.y, dv * hv.z, dv * hv.w);
        int e = 0;
        for (; e + 8 <= end; e += 8) {
            int s0 = r[e],     s1 = r[e + 1], s2 = r[e + 2], s3 = r[e + 3];
            int s4 = r[e + 4], s5 = r[e + 5], s6 = r[e + 6], s7 = r[e + 7];
            float4 h0 = x[(size_t)s0 * 4 + lane];
            float4 h1 = x[(size_t)s1 * 4 + lane];
            float4 h2 = x[(size_t)s2 * 4 + lane];
            float4 h3 = x[(size_t)s3 * 4 + lane];
            float4 h4 = x[(size_t)s4 * 4 + lane];
            float4 h5 = x[(size_t)s5 * 4 + lane];
            float4 h6 = x[(size_t)s6 * 4 + lane];
            float4 h7 = x[(size_t)s7 * 4 + lane];
            float w0 = dinv_of(cnt, s0), w1 = dinv_of(cnt, s1);
            float w2 = dinv_of(cnt, s2), w3 = dinv_of(cnt, s3);
            float w4 = dinv_of(cnt, s4), w5 = dinv_of(cnt, s5);
            float w6 = dinv_of(cnt, s6), w7 = dinv_of(cnt, s7);
            if (lane == 0) {
                *(float4*)(wrow + e)     = make_float4(w0 * sc, w1 * sc, w2 * sc, w3 * sc);
                *(float4*)(wrow + e + 4) = make_float4(w4 * sc, w5 * sc, w6 * sc, w7 * sc);
            }
            acc.x += w0 * h0.x + w1 * h1.x + w2 * h2.x + w3 * h3.x
                   + w4 * h4.x + w5 * h5.x + w6 * h6.x + w7 * h7.x;
            acc.y += w0 * h0.y + w1 * h1.y + w2 * h2.y + w3 * h3.y
                   + w4 * h4.y + w5 * h5.y + w6 * h6.y + w7 * h7.y;
            acc.z += w0 * h0.z + w1 * h1.z + w2 * h2.z + w3 * h3.z
                   + w4 * h4.z + w5 * h5.z + w6 * h6.z + w7 * h7.z;
            acc.w += w0 * h0.w + w1 * h1.w + w2 * h2.w + w3 * h3.w
                   + w4 * h4.w + w5 * h5.w + w6 * h6.w + w7 * h7.w;
        }
        for (; e + 4 <= end; e += 4) {
            int s0 = r[e], s1 = r[e + 1], s2 = r[e + 2], s3 = r[e + 3];
            float4 h0 = x[(size_t)s0 * 4 + lane];
            float4 h1 = x[(size_t)s1 * 4 + lane];
            float4 h2 = x[(size_t)s2 * 4 + lane];
            float4 h3 = x[(size_t)s3 * 4 + lane];
            float w0 = dinv_of(cnt, s0), w1 = dinv_of(cnt, s1);
            float w2 = dinv_of(cnt, s2), w3 = dinv_of(cnt, s3);
            if (lane == 0)
                *(float4*)(wrow + e) = make_float4(w0 * sc, w1 * sc, w2 * sc, w3 * sc);
            acc.x += w0 * h0.x + w1 * h1.x + w2 * h2.x + w3 * h3.x;
            acc.y += w0 * h0.y + w1 * h1.y + w2 * h2.y + w3 * h3.y;
            acc.z += w0 * h0.z + w1 * h1.z + w2 * h2.z + w3 * h3.z;
            acc.w += w0 * h0.w + w1 * h1.w + w2 * h2.w + w3 * h3.w;
        }
        for (; e < end; e++) {
            int s = r[e];
            float w = dinv_of(cnt, s);
            if (lane == 0) wrow[e] = w * sc;
            float4 hs = x[(size_t)s * 4 + lane];
            acc.x += w * hs.x; acc.y += w * hs.y; acc.z += w * hs.z; acc.w += w * hs.w;
        }
        sagg[grp][lane * 4 + 0] = acc.x * sc;
        sagg[grp][lane * 4 + 1] = acc.y * sc;
        sagg[grp][lane * 4 + 2] = acc.z * sc;
        sagg[grp][lane * 4 + 3] = acc.w * sc;
    }
    __syncthreads();

    int vg = tid >> 2;
    int c0 = (tid & 3) * 16;
    int vout = blockIdx.x * 64 + vg;
    if (vout >= n) return;
    float o[16];
    #pragma unroll
    for (int jj = 0; jj < 16; jj++) o[jj] = sb[c0 + jj];
    #pragma unroll
    for (int k = 0; k < 16; k++) {
        float a = sagg[vg][k];
        #pragma unroll
        for (int jj = 0; jj < 16; jj++) o[jj] += a * sW[k * 64 + c0 + jj];
    }
    short8 p0, p1;
    #pragma unroll
    for (int jj = 0; jj < 8; jj++) p0[jj] = (short)f2bf(fmaxf(o[jj], 0.0f));
    #pragma unroll
    for (int jj = 0; jj < 8; jj++) p1[jj] = (short)f2bf(fmaxf(o[jj + 8], 0.0f));
    *(short8*)(h_out + (size_t)vout * 64 + c0) = p0;
    *(short8*)(h_out + (size_t)vout * 64 + c0 + 8) = p1;
}

// ---------------- bf16 ELL pre-aggregation (layers 2..4), unroll-8 ----------
// Precomputed full weights: out = selfw*hv + sum ellw[e]*hs; selfw = inv_cnt^2.

__global__ void k_agg_ell_bf16(const short8* __restrict__ h, short8* __restrict__ out,
                               const int* __restrict__ ell, const int* __restrict__ cnt,
                               const float* __restrict__ ellw, int n, int g_shift) {
    int g = 1 << g_shift;                        // lanes per node = d/8
    int grp = threadIdx.x >> g_shift;
    int lane = threadIdx.x & (g - 1);
    int gpb = blockDim.x >> g_shift;
    int v = blockIdx.x * gpb + grp;
    if (v >= n) return;
    int end = cnt[v];
    float inv_cnt = 1.0f / (float)(end + 1);
    float selfw = inv_cnt * inv_cnt;             // dv^2 * inv_cnt, dv^2 == inv_cnt
    const int* r = ell + ((size_t)v << 6);
    const float* wrow = ellw + ((size_t)v << 6);

    float acc[8];
    short8 hv = h[(size_t)v * g + lane];
    #pragma unroll
    for (int i = 0; i < 8; i++) acc[i] = selfw * bf2f(hv[i]);

    int e = 0;
    for (; e + 8 <= end; e += 8) {
        int s0 = r[e],     s1 = r[e + 1], s2 = r[e + 2], s3 = r[e + 3];
        int s4 = r[e + 4], s5 = r[e + 5], s6 = r[e + 6], s7 = r[e + 7];
        float4 wA = *(const float4*)(wrow + e);
        float4 wB = *(const float4*)(wrow + e + 4);
        short8 h0 = h[(size_t)s0 * g + lane];
        short8 h1 = h[(size_t)s1 * g + lane];
        short8 h2 = h[(size_t)s2 * g + lane];
        short8 h3 = h[(size_t)s3 * g + lane];
        short8 h4 = h[(size_t)s4 * g + lane];
        short8 h5 = h[(size_t)s5 * g + lane];
        short8 h6 = h[(size_t)s6 * g + lane];
        short8 h7 = h[(size_t)s7 * g + lane];
        #pragma unroll
        for (int i = 0; i < 8; i++)
            acc[i] += wA.x * bf2f(h0[i]) + wA.y * bf2f(h1[i])
                    + wA.z * bf2f(h2[i]) + wA.w * bf2f(h3[i])
                    + wB.x * bf2f(h4[i]) + wB.y * bf2f(h5[i])
                    + wB.z * bf2f(h6[i]) + wB.w * bf2f(h7[i]);
    }
    for (; e + 4 <= end; e += 4) {
        int s0 = r[e], s1 = r[e + 1], s2 = r[e + 2], s3 = r[e + 3];
        float4 wA = *(const float4*)(wrow + e);
        short8 h0 = h[(size_t)s0 * g + lane];
        short8 h1 = h[(size_t)s1 * g + lane];
        short8 h2 = h[(size_t)s2 * g + lane];
        short8 h3 = h[(size_t)s3 * g + lane];
        #pragma unroll
        for (int i = 0; i < 8; i++)
            acc[i] += wA.x * bf2f(h0[i]) + wA.y * bf2f(h1[i])
                    + wA.z * bf2f(h2[i]) + wA.w * bf2f(h3[i]);
    }
    for (; e < end; e++) {
        int s0 = r[e];
        float w0 = wrow[e];
        short8 h0 = h[(size_t)s0 * g + lane];
        #pragma unroll
        for (int i = 0; i < 8; i++) acc[i] += w0 * bf2f(h0[i]);
    }
    short8 o;
    #pragma unroll
    for (int i = 0; i < 8; i++) o[i] = (short)f2bf(acc[i]);
    out[(size_t)v * g + lane] = o;
}

// ---------------- MFMA GEMM: C_bf16[M,N] = relu(A[M,K] @ Wt[N,K]^T + bias) --
// M padded to 128 multiple, K/N exact multiples -> no bounds checks at all.
// Reg-prefetch of next K-tile. dotw != nullptr: fused final-layer dot into z.

#define GBM 128
#define GBN 128
#define GBK 32
#define LDSS 40   // LDS row stride in elements (80B, 16B-aligned)

__global__ __launch_bounds__(256) void gemm_mfma(const ushort* __restrict__ A,
                                                 const ushort* __restrict__ Wt,
                                                 const float* __restrict__ bias,
                                                 ushort* __restrict__ C,
                                                 const float* __restrict__ dotw,
                                                 float* __restrict__ z,
                                                 int K, int N, int do_relu) {
    __shared__ ushort As[GBM * LDSS];
    __shared__ ushort Bs[GBN * LDSS];
    int tid = threadIdx.x;
    int wave = tid >> 6;
    int lane = tid & 63;
    int wr = wave >> 1, wc = wave & 1;
    int q = lane >> 4;          // quad 0..3
    int mr = lane & 15;
    int row0 = blockIdx.y * GBM;
    int col0 = blockIdx.x * GBN;

    int sr = tid >> 2;          // staging row 0..63 (and sr+64)
    int skoff = (tid & 3) * 8;  // staging k offset

    f32x4 acc[4][4];
    #pragma unroll
    for (int i = 0; i < 4; i++)
        #pragma unroll
        for (int j = 0; j < 4; j++) acc[i][j] = (f32x4){0.f, 0.f, 0.f, 0.f};

    short8 va0, va1, vb0, vb1;
    int gn0 = col0 + sr, gn1 = col0 + sr + 64;

    {
        va0 = *(const short8*)(A + (size_t)(row0 + sr) * K + skoff);
        va1 = *(const short8*)(A + (size_t)(row0 + sr + 64) * K + skoff);
        vb0 = *(const short8*)(Wt + (size_t)gn0 * K + skoff);
        vb1 = *(const short8*)(Wt + (size_t)gn1 * K + skoff);
        *(short8*)(As + sr * LDSS + skoff) = va0;
        *(short8*)(As + (sr + 64) * LDSS + skoff) = va1;
        *(short8*)(Bs + sr * LDSS + skoff) = vb0;
        *(short8*)(Bs + (sr + 64) * LDSS + skoff) = vb1;
    }
    __syncthreads();

    for (int k0 = 0;;) {
        int k1 = k0 + GBK;
        bool more = (k1 < K);
        if (more) {                       // prefetch next tile into registers
            int gk = k1 + skoff;
            va0 = *(const short8*)(A + (size_t)(row0 + sr) * K + gk);
            va1 = *(const short8*)(A + (size_t)(row0 + sr + 64) * K + gk);
            vb0 = *(const short8*)(Wt + (size_t)gn0 * K + gk);
            vb1 = *(const short8*)(Wt + (size_t)gn1 * K + gk);
        }
        short8 afr[4], bfr[4];
        #pragma unroll
        for (int i = 0; i < 4; i++)
            afr[i] = *(const short8*)(As + (wr * 64 + i * 16 + mr) * LDSS + q * 8);
        #pragma unroll
        for (int j = 0; j < 4; j++)
            bfr[j] = *(const short8*)(Bs + (wc * 64 + j * 16 + mr) * LDSS + q * 8);
        #pragma unroll
        for (int i = 0; i < 4; i++)
            #pragma unroll
            for (int j = 0; j < 4; j++)
                acc[i][j] = __builtin_amdgcn_mfma_f32_16x16x32_bf16(afr[i], bfr[j],
                                                                    acc[i][j], 0, 0, 0);
        if (!more) break;
        __syncthreads();
        *(short8*)(As + sr * LDSS + skoff) = va0;
        *(short8*)(As + (sr + 64) * LDSS + skoff) = va1;
        *(short8*)(Bs + sr * LDSS + skoff) = vb0;
        *(short8*)(Bs + (sr + 64) * LDSS + skoff) = vb1;
        __syncthreads();
        k0 = k1;
    }

    if (dotw) {
        // fused final-layer dot: z[row] += sum_col relu(acc+bias)*dotw[col]
        float bj[4], wj[4];
        #pragma unroll
        for (int j = 0; j < 4; j++) {
            int col = col0 + wc * 64 + j * 16 + mr;
            bj[j] = bias[col];
            wj[j] = dotw[col];
        }
        #pragma unroll
        for (int i = 0; i < 4; i++) {
            #pragma unroll
            for (int r = 0; r < 4; r++) {
                float p = 0.0f;
                #pragma unroll
                for (int j = 0; j < 4; j++)
                    p += fmaxf(acc[i][j][r] + bj[j], 0.0f) * wj[j];
                #pragma unroll
                for (int off = 1; off < 16; off <<= 1)
                    p += __shfl_xor(p, off, 64);   // reduce over mr within quad
                if (mr == 0)
                    atomicAdd(&z[row0 + wr * 64 + i * 16 + q * 4 + r], p);
            }
        }
        return;
    }

    // epilogue: C/D layout col=lane&15, row=q*4+reg; emit bf16
    #pragma unroll
    for (int j = 0; j < 4; j++) {
        int col = col0 + wc * 64 + j * 16 + mr;
        float bj = bias[col];
        #pragma unroll
        for (int i = 0; i < 4; i++) {
            int rbase = row0 + wr * 64 + i * 16 + q * 4;
            #pragma unroll
            for (int r = 0; r < 4; r++) {
                float v = acc[i][j][r] + bj;
                if (do_relu) v = fmaxf(v, 0.0f);
                C[(size_t)(rbase + r) * N + col] = f2bf(v);
            }
        }
    }
}

// ---------------- final: add-aggregate z + bias + sigmoid ----------------

__global__ void k_agg_final(const float* __restrict__ h, float* __restrict__ out,
                            const int* __restrict__ ell, const int* __restrict__ cnt,
                            const float* __restrict__ b5, int n) {
    int v = blockIdx.x * blockDim.x + threadIdx.x;
    if (v >= n) return;
    float dv = dinv_of(cnt, v);
    float acc = dv * h[v];
    int end = cnt[v];
    const int* r = ell + ((size_t)v << 6);
    for (int e = 0; e < end; e++) {
        int s = r[e];
        acc += dinv_of(cnt, s) * h[s];
    }
    float rr = dv * acc + b5[0];
    out[v] = 1.0f / (1.0f + expf(-rr));
}

// ---------------- launch ----------------

extern "C" void kernel_launch(void* const* d_in, const int* in_sizes, int n_in,
                              void* d_out, int out_size, void* d_ws, size_t ws_size,
                              hipStream_t stream) {
    const float* x   = (const float*)d_in[0];
    const int*   ei  = (const int*)d_in[1];
    const float* W[5] = {(const float*)d_in[2], (const float*)d_in[4], (const float*)d_in[6],
                         (const float*)d_in[8], (const float*)d_in[10]};
    const float* b[5] = {(const float*)d_in[3], (const float*)d_in[5], (const float*)d_in[7],
                         (const float*)d_in[9], (const float*)d_in[11]};
    const int n = in_sizes[0] / 16;
    const int E = in_sizes[1] / 2;

    const int* e_row = ei;          // src
    const int* e_col = ei + E;      // dst

    // workspace layout
    float* bufA_f = (float*)d_ws;                     // n*512 floats region
    float* bufB_f = bufA_f + (size_t)n * 512;         // n*512 floats region
    ushort* bufA  = (ushort*)bufA_f;                  // h (GEMM out, bf16)
    ushort* bufB  = (ushort*)bufB_f;                  // agg out (bf16)
    int*   cnt    = (int*)(bufB_f + (size_t)n * 512); // n
    int*   ell    = cnt + n;                          // n * ELLW
    ushort* wt2   = (ushort*)(ell + (size_t)n * ELLW);
    ushort* wt3   = wt2 + 64 * 128;
    ushort* wt4   = wt3 + 128 * 256;
    float* ellw   = (float*)(wt4 + 256 * 512);        // n * ELLW floats
    float* z      = ellw + (size_t)n * ELLW;          // Mpad floats

    const int Mpad = (n + GBM - 1) / GBM * GBM;       // 20096

    // ---- prep ----
    k_zero<<<(Mpad + 255) / 256, 256, 0, stream>>>(cnt, z, n, Mpad);
    k_fill_ell<<<(E + 255) / 256, 256, 0, stream>>>(e_row, e_col, cnt, ell, E,
                                                    W[1], W[2], W[3], wt2, wt3, wt4);

    // ---- layer 1: fused agg(d=16) + 16x64 GEMM + relu -> bf16 h ----
    k_l1_fused<<<(n + 63) / 64, 256, 0, stream>>>(
        (const float4*)x, bufA, ell, cnt, ellw, W[0], b[0], n);

    // ---- layer 2 ----
    k_agg_ell_bf16<<<(n + 31) / 32, 256, 0, stream>>>(
        (const short8*)bufA, (short8*)bufB, ell, cnt, ellw, n, 3);
    {
        dim3 ggrid(128 / GBN, Mpad / GBM);
        gemm_mfma<<<ggrid, 256, 0, stream>>>(bufB, wt2, b[1], bufA,
                                             nullptr, nullptr, 64, 128, 1);
    }

    // ---- layer 3 ----
    k_agg_ell_bf16<<<(n + 15) / 16, 256, 0, stream>>>(
        (const short8*)bufA, (short8*)bufB, ell, cnt, ellw, n, 4);
    {
        dim3 ggrid(256 / GBN, Mpad / GBM);
        gemm_mfma<<<ggrid, 256, 0, stream>>>(bufB, wt3, b[2], bufA,
                                             nullptr, nullptr, 128, 256, 1);
    }

    // ---- layer 4 + fused layer-5 dot ----
    k_agg_ell_bf16<<<(n + 7) / 8, 256, 0, stream>>>(
        (const short8*)bufA, (short8*)bufB, ell, cnt, ellw, n, 5);
    {
        dim3 ggrid(512 / GBN, Mpad / GBM);
        gemm_mfma<<<ggrid, 256, 0, stream>>>(bufB, wt4, b[3], nullptr,
                                             W[4], z, 256, 512, 1);
    }

    // ---- layer 5: add-aggregate + sigmoid ----
    k_agg_final<<<(n + 255) / 256, 256, 0, stream>>>(z, (float*)d_out, ell, cnt,
                                                     b[4], n);
}

// Round 8
// 200.437 us; speedup vs baseline: 5.4570x; 1.0270x over previous
//
#include <hip/hip_runtime.h>
#include <hip/hip_bf16.h>
#include <hip/hip_fp8.h>
#include <math.h>

// GCN 5-layer: dims 16->64->128->256->512->1, N=20000, E=320000.
// Round 17: r16 base + fp8(e4m3, OCP) storage for H3 only. H3 is consumed
// solely by the layer-4 aggregation gather (the single biggest memory item:
// E*512B = 164 MB from a 10 MB L3-resident working set). GEMM3's epilogue
// writes fp8 directly (10->5 MB write) and the L4 agg gathers 8 B/lane
// (164->82 MB). fp32 accumulate unchanged; one quantization step added.

#define N_NODES 20000
#define N_EDGES 320000
#define ELLW 64   // P(in-deg >= 48) ~ 1e-10 for Poisson(16)

typedef __attribute__((ext_vector_type(8))) short short8;
typedef __attribute__((ext_vector_type(8))) unsigned char uchar8;
typedef __attribute__((ext_vector_type(4))) float f32x4;

__device__ inline ushort f2bf(float f) {
    __hip_bfloat16 h = __float2bfloat16(f);   // RNE
    return *(ushort*)&h;
}

__device__ inline float bf2f(short s) {
    union { unsigned int u; float f; } c;
    c.u = ((unsigned int)(unsigned short)s) << 16;
    return c.f;
}

__device__ inline unsigned char f2fp8(float f) {
    __hip_fp8_e4m3 q(f);
    return *reinterpret_cast<unsigned char*>(&q);
}

__device__ inline float fp82f(unsigned char u) {
    __hip_fp8_e4m3 q = *reinterpret_cast<__hip_fp8_e4m3*>(&u);
    return (float)q;
}

__device__ __forceinline__ float dinv_of(const int* __restrict__ cnt, int v) {
    return rsqrtf((float)(cnt[v] + 1));       // in-degree + self-loop
}

// ---------------- prep: zero cnt + z ----------------

__global__ void k_zero(int* __restrict__ cnt, float* __restrict__ z, int n, int mpad) {
    int i = blockIdx.x * blockDim.x + threadIdx.x;
    if (i < n) cnt[i] = 0;
    if (i < mpad) z[i] = 0.0f;
}

// ---------------- ELL build + weight transposes (ride the same grid) --------

__global__ void k_fill_ell(const int* __restrict__ row, const int* __restrict__ col,
                           int* __restrict__ cnt, int* __restrict__ ell, int E,
                           const float* __restrict__ W2, const float* __restrict__ W3,
                           const float* __restrict__ W4,
                           ushort* __restrict__ T2, ushort* __restrict__ T3,
                           ushort* __restrict__ T4) {
    int e = blockIdx.x * blockDim.x + threadIdx.x;
    if (e < 172032) {
        const float* W; ushort* T; int K, N, j;
        if (e < 8192)        { W = W2; T = T2; K = 64;  N = 128; j = e; }
        else if (e < 40960)  { W = W3; T = T3; K = 128; N = 256; j = e - 8192; }
        else                 { W = W4; T = T4; K = 256; N = 512; j = e - 40960; }
        int nn = j / K, kk = j - nn * K;
        T[(size_t)nn * K + kk] = f2bf(W[(size_t)kk * N + nn]);
    }
    if (e >= E) return;
    int s = row[e], d = col[e];
    int pos = atomicAdd(&cnt[d], 1);
    ell[((size_t)d << 6) + pos] = s;
}

// ---------------- layer 1 fused: agg(d=16, fp32) + GEMM 16x64 + relu --------
// Lane 0 of each node group also stores w_full = dinv_s * dv * inv_cnt.

__global__ __launch_bounds__(256) void k_l1_fused(const float4* __restrict__ x,
                                                  ushort* __restrict__ h_out,
                                                  const int* __restrict__ ell,
                                                  const int* __restrict__ cnt,
                                                  float* __restrict__ ellw,
                                                  const float* __restrict__ W,
                                                  const float* __restrict__ b, int n) {
    __shared__ float sW[16 * 64];
    __shared__ float sb[64];
    __shared__ float sagg[64][17];    // padded: avoid bank conflicts
    int tid = threadIdx.x;
    #pragma unroll
    for (int i = tid; i < 1024; i += 256) sW[i] = W[i];
    if (tid < 64) sb[tid] = b[tid];

    int grp = tid >> 2;               // node within block
    int lane = tid & 3;               // float4 lane (4 feats each)
    int v = blockIdx.x * 64 + grp;
    if (v < n) {
        float dv = dinv_of(cnt, v);
        int end = cnt[v];
        float inv_cnt = 1.0f / (float)(end + 1);
        float sc = dv * inv_cnt;
        const int* r = ell + ((size_t)v << 6);
        float* wrow = ellw + ((size_t)v << 6);
        float4 hv = x[(size_t)v * 4 + lane];
        float4 acc = make_float4(dv * hv.x, dv * hv.y, dv * hv.z, dv * hv.w);
        int e = 0;
        for (; e + 8 <= end; e += 8) {
            int s0 = r[e],     s1 = r[e + 1], s2 = r[e + 2], s3 = r[e + 3];
            int s4 = r[e + 4], s5 = r[e + 5], s6 = r[e + 6], s7 = r[e + 7];
            float4 h0 = x[(size_t)s0 * 4 + lane];
            float4 h1 = x[(size_t)s1 * 4 + lane];
            float4 h2 = x[(size_t)s2 * 4 + lane];
            float4 h3 = x[(size_t)s3 * 4 + lane];
            float4 h4 = x[(size_t)s4 * 4 + lane];
            float4 h5 = x[(size_t)s5 * 4 + lane];
            float4 h6 = x[(size_t)s6 * 4 + lane];
            float4 h7 = x[(size_t)s7 * 4 + lane];
            float w0 = dinv_of(cnt, s0), w1 = dinv_of(cnt, s1);
            float w2 = dinv_of(cnt, s2), w3 = dinv_of(cnt, s3);
            float w4 = dinv_of(cnt, s4), w5 = dinv_of(cnt, s5);
            float w6 = dinv_of(cnt, s6), w7 = dinv_of(cnt, s7);
            if (lane == 0) {
                *(float4*)(wrow + e)     = make_float4(w0 * sc, w1 * sc, w2 * sc, w3 * sc);
                *(float4*)(wrow + e + 4) = make_float4(w4 * sc, w5 * sc, w6 * sc, w7 * sc);
            }
            acc.x += w0 * h0.x + w1 * h1.x + w2 * h2.x + w3 * h3.x
                   + w4 * h4.x + w5 * h5.x + w6 * h6.x + w7 * h7.x;
            acc.y += w0 * h0.y + w1 * h1.y + w2 * h2.y + w3 * h3.y
                   + w4 * h4.y + w5 * h5.y + w6 * h6.y + w7 * h7.y;
            acc.z += w0 * h0.z + w1 * h1.z + w2 * h2.z + w3 * h3.z
                   + w4 * h4.z + w5 * h5.z + w6 * h6.z + w7 * h7.z;
            acc.w += w0 * h0.w + w1 * h1.w + w2 * h2.w + w3 * h3.w
                   + w4 * h4.w + w5 * h5.w + w6 * h6.w + w7 * h7.w;
        }
        for (; e + 4 <= end; e += 4) {
            int s0 = r[e], s1 = r[e + 1], s2 = r[e + 2], s3 = r[e + 3];
            float4 h0 = x[(size_t)s0 * 4 + lane];
            float4 h1 = x[(size_t)s1 * 4 + lane];
            float4 h2 = x[(size_t)s2 * 4 + lane];
            float4 h3 = x[(size_t)s3 * 4 + lane];
            float w0 = dinv_of(cnt, s0), w1 = dinv_of(cnt, s1);
            float w2 = dinv_of(cnt, s2), w3 = dinv_of(cnt, s3);
            if (lane == 0)
                *(float4*)(wrow + e) = make_float4(w0 * sc, w1 * sc, w2 * sc, w3 * sc);
            acc.x += w0 * h0.x + w1 * h1.x + w2 * h2.x + w3 * h3.x;
            acc.y += w0 * h0.y + w1 * h1.y + w2 * h2.y + w3 * h3.y;
            acc.z += w0 * h0.z + w1 * h1.z + w2 * h2.z + w3 * h3.z;
            acc.w += w0 * h0.w + w1 * h1.w + w2 * h2.w + w3 * h3.w;
        }
        for (; e < end; e++) {
            int s = r[e];
            float w = dinv_of(cnt, s);
            if (lane == 0) wrow[e] = w * sc;
            float4 hs = x[(size_t)s * 4 + lane];
            acc.x += w * hs.x; acc.y += w * hs.y; acc.z += w * hs.z; acc.w += w * hs.w;
        }
        sagg[grp][lane * 4 + 0] = acc.x * sc;
        sagg[grp][lane * 4 + 1] = acc.y * sc;
        sagg[grp][lane * 4 + 2] = acc.z * sc;
        sagg[grp][lane * 4 + 3] = acc.w * sc;
    }
    __syncthreads();

    int vg = tid >> 2;
    int c0 = (tid & 3) * 16;
    int vout = blockIdx.x * 64 + vg;
    if (vout >= n) return;
    float o[16];
    #pragma unroll
    for (int jj = 0; jj < 16; jj++) o[jj] = sb[c0 + jj];
    #pragma unroll
    for (int k = 0; k < 16; k++) {
        float a = sagg[vg][k];
        #pragma unroll
        for (int jj = 0; jj < 16; jj++) o[jj] += a * sW[k * 64 + c0 + jj];
    }
    short8 p0, p1;
    #pragma unroll
    for (int jj = 0; jj < 8; jj++) p0[jj] = (short)f2bf(fmaxf(o[jj], 0.0f));
    #pragma unroll
    for (int jj = 0; jj < 8; jj++) p1[jj] = (short)f2bf(fmaxf(o[jj + 8], 0.0f));
    *(short8*)(h_out + (size_t)vout * 64 + c0) = p0;
    *(short8*)(h_out + (size_t)vout * 64 + c0 + 8) = p1;
}

// ---------------- bf16 ELL pre-aggregation (layers 2..3), unroll-8 ----------
// Precomputed full weights: out = selfw*hv + sum ellw[e]*hs; selfw = inv_cnt^2.

__global__ void k_agg_ell_bf16(const short8* __restrict__ h, short8* __restrict__ out,
                               const int* __restrict__ ell, const int* __restrict__ cnt,
                               const float* __restrict__ ellw, int n, int g_shift) {
    int g = 1 << g_shift;                        // lanes per node = d/8
    int grp = threadIdx.x >> g_shift;
    int lane = threadIdx.x & (g - 1);
    int gpb = blockDim.x >> g_shift;
    int v = blockIdx.x * gpb + grp;
    if (v >= n) return;
    int end = cnt[v];
    float inv_cnt = 1.0f / (float)(end + 1);
    float selfw = inv_cnt * inv_cnt;             // dv^2 * inv_cnt, dv^2 == inv_cnt
    const int* r = ell + ((size_t)v << 6);
    const float* wrow = ellw + ((size_t)v << 6);

    float acc[8];
    short8 hv = h[(size_t)v * g + lane];
    #pragma unroll
    for (int i = 0; i < 8; i++) acc[i] = selfw * bf2f(hv[i]);

    int e = 0;
    for (; e + 8 <= end; e += 8) {
        int s0 = r[e],     s1 = r[e + 1], s2 = r[e + 2], s3 = r[e + 3];
        int s4 = r[e + 4], s5 = r[e + 5], s6 = r[e + 6], s7 = r[e + 7];
        float4 wA = *(const float4*)(wrow + e);
        float4 wB = *(const float4*)(wrow + e + 4);
        short8 h0 = h[(size_t)s0 * g + lane];
        short8 h1 = h[(size_t)s1 * g + lane];
        short8 h2 = h[(size_t)s2 * g + lane];
        short8 h3 = h[(size_t)s3 * g + lane];
        short8 h4 = h[(size_t)s4 * g + lane];
        short8 h5 = h[(size_t)s5 * g + lane];
        short8 h6 = h[(size_t)s6 * g + lane];
        short8 h7 = h[(size_t)s7 * g + lane];
        #pragma unroll
        for (int i = 0; i < 8; i++)
            acc[i] += wA.x * bf2f(h0[i]) + wA.y * bf2f(h1[i])
                    + wA.z * bf2f(h2[i]) + wA.w * bf2f(h3[i])
                    + wB.x * bf2f(h4[i]) + wB.y * bf2f(h5[i])
                    + wB.z * bf2f(h6[i]) + wB.w * bf2f(h7[i]);
    }
    for (; e + 4 <= end; e += 4) {
        int s0 = r[e], s1 = r[e + 1], s2 = r[e + 2], s3 = r[e + 3];
        float4 wA = *(const float4*)(wrow + e);
        short8 h0 = h[(size_t)s0 * g + lane];
        short8 h1 = h[(size_t)s1 * g + lane];
        short8 h2 = h[(size_t)s2 * g + lane];
        short8 h3 = h[(size_t)s3 * g + lane];
        #pragma unroll
        for (int i = 0; i < 8; i++)
            acc[i] += wA.x * bf2f(h0[i]) + wA.y * bf2f(h1[i])
                    + wA.z * bf2f(h2[i]) + wA.w * bf2f(h3[i]);
    }
    for (; e < end; e++) {
        int s0 = r[e];
        float w0 = wrow[e];
        short8 h0 = h[(size_t)s0 * g + lane];
        #pragma unroll
        for (int i = 0; i < 8; i++) acc[i] += w0 * bf2f(h0[i]);
    }
    short8 o;
    #pragma unroll
    for (int i = 0; i < 8; i++) o[i] = (short)f2bf(acc[i]);
    out[(size_t)v * g + lane] = o;
}

// ---------------- fp8-input ELL aggregation (layer 4: H3 is fp8) ------------

__global__ void k_agg_ell_fp8(const uchar8* __restrict__ h, short8* __restrict__ out,
                              const int* __restrict__ ell, const int* __restrict__ cnt,
                              const float* __restrict__ ellw, int n, int g_shift) {
    int g = 1 << g_shift;                        // lanes per node = d/8
    int grp = threadIdx.x >> g_shift;
    int lane = threadIdx.x & (g - 1);
    int gpb = blockDim.x >> g_shift;
    int v = blockIdx.x * gpb + grp;
    if (v >= n) return;
    int end = cnt[v];
    float inv_cnt = 1.0f / (float)(end + 1);
    float selfw = inv_cnt * inv_cnt;
    const int* r = ell + ((size_t)v << 6);
    const float* wrow = ellw + ((size_t)v << 6);

    float acc[8];
    uchar8 hv = h[(size_t)v * g + lane];
    #pragma unroll
    for (int i = 0; i < 8; i++) acc[i] = selfw * fp82f(hv[i]);

    int e = 0;
    for (; e + 8 <= end; e += 8) {
        int s0 = r[e],     s1 = r[e + 1], s2 = r[e + 2], s3 = r[e + 3];
        int s4 = r[e + 4], s5 = r[e + 5], s6 = r[e + 6], s7 = r[e + 7];
        float4 wA = *(const float4*)(wrow + e);
        float4 wB = *(const float4*)(wrow + e + 4);
        uchar8 h0 = h[(size_t)s0 * g + lane];
        uchar8 h1 = h[(size_t)s1 * g + lane];
        uchar8 h2 = h[(size_t)s2 * g + lane];
        uchar8 h3 = h[(size_t)s3 * g + lane];
        uchar8 h4 = h[(size_t)s4 * g + lane];
        uchar8 h5 = h[(size_t)s5 * g + lane];
        uchar8 h6 = h[(size_t)s6 * g + lane];
        uchar8 h7 = h[(size_t)s7 * g + lane];
        #pragma unroll
        for (int i = 0; i < 8; i++)
            acc[i] += wA.x * fp82f(h0[i]) + wA.y * fp82f(h1[i])
                    + wA.z * fp82f(h2[i]) + wA.w * fp82f(h3[i])
                    + wB.x * fp82f(h4[i]) + wB.y * fp82f(h5[i])
                    + wB.z * fp82f(h6[i]) + wB.w * fp82f(h7[i]);
    }
    for (; e + 4 <= end; e += 4) {
        int s0 = r[e], s1 = r[e + 1], s2 = r[e + 2], s3 = r[e + 3];
        float4 wA = *(const float4*)(wrow + e);
        uchar8 h0 = h[(size_t)s0 * g + lane];
        uchar8 h1 = h[(size_t)s1 * g + lane];
        uchar8 h2 = h[(size_t)s2 * g + lane];
        uchar8 h3 = h[(size_t)s3 * g + lane];
        #pragma unroll
        for (int i = 0; i < 8; i++)
            acc[i] += wA.x * fp82f(h0[i]) + wA.y * fp82f(h1[i])
                    + wA.z * fp82f(h2[i]) + wA.w * fp82f(h3[i]);
    }
    for (; e < end; e++) {
        int s0 = r[e];
        float w0 = wrow[e];
        uchar8 h0 = h[(size_t)s0 * g + lane];
        #pragma unroll
        for (int i = 0; i < 8; i++) acc[i] += w0 * fp82f(h0[i]);
    }
    short8 o;
    #pragma unroll
    for (int i = 0; i < 8; i++) o[i] = (short)f2bf(acc[i]);
    out[(size_t)v * g + lane] = o;
}

// ---------------- MFMA GEMM: C = relu(A[M,K] @ Wt[N,K]^T + bias) ------------
// M padded to 128 multiple, K/N exact multiples -> no bounds checks.
// C8 != nullptr: emit fp8 e4m3. dotw != nullptr: fused final dot into z.

#define GBM 128
#define GBN 128
#define GBK 32
#define LDSS 40   // LDS row stride in elements (80B, 16B-aligned)

__global__ __launch_bounds__(256) void gemm_mfma(const ushort* __restrict__ A,
                                                 const ushort* __restrict__ Wt,
                                                 const float* __restrict__ bias,
                                                 ushort* __restrict__ C,
                                                 unsigned char* __restrict__ C8,
                                                 const float* __restrict__ dotw,
                                                 float* __restrict__ z,
                                                 int K, int N, int do_relu) {
    __shared__ ushort As[GBM * LDSS];
    __shared__ ushort Bs[GBN * LDSS];
    int tid = threadIdx.x;
    int wave = tid >> 6;
    int lane = tid & 63;
    int wr = wave >> 1, wc = wave & 1;
    int q = lane >> 4;          // quad 0..3
    int mr = lane & 15;
    int row0 = blockIdx.y * GBM;
    int col0 = blockIdx.x * GBN;

    int sr = tid >> 2;          // staging row 0..63 (and sr+64)
    int skoff = (tid & 3) * 8;  // staging k offset

    f32x4 acc[4][4];
    #pragma unroll
    for (int i = 0; i < 4; i++)
        #pragma unroll
        for (int j = 0; j < 4; j++) acc[i][j] = (f32x4){0.f, 0.f, 0.f, 0.f};

    short8 va0, va1, vb0, vb1;
    int gn0 = col0 + sr, gn1 = col0 + sr + 64;

    {
        va0 = *(const short8*)(A + (size_t)(row0 + sr) * K + skoff);
        va1 = *(const short8*)(A + (size_t)(row0 + sr + 64) * K + skoff);
        vb0 = *(const short8*)(Wt + (size_t)gn0 * K + skoff);
        vb1 = *(const short8*)(Wt + (size_t)gn1 * K + skoff);
        *(short8*)(As + sr * LDSS + skoff) = va0;
        *(short8*)(As + (sr + 64) * LDSS + skoff) = va1;
        *(short8*)(Bs + sr * LDSS + skoff) = vb0;
        *(short8*)(Bs + (sr + 64) * LDSS + skoff) = vb1;
    }
    __syncthreads();

    for (int k0 = 0;;) {
        int k1 = k0 + GBK;
        bool more = (k1 < K);
        if (more) {                       // prefetch next tile into registers
            int gk = k1 + skoff;
            va0 = *(const short8*)(A + (size_t)(row0 + sr) * K + gk);
            va1 = *(const short8*)(A + (size_t)(row0 + sr + 64) * K + gk);
            vb0 = *(const short8*)(Wt + (size_t)gn0 * K + gk);
            vb1 = *(const short8*)(Wt + (size_t)gn1 * K + gk);
        }
        short8 afr[4], bfr[4];
        #pragma unroll
        for (int i = 0; i < 4; i++)
            afr[i] = *(const short8*)(As + (wr * 64 + i * 16 + mr) * LDSS + q * 8);
        #pragma unroll
        for (int j = 0; j < 4; j++)
            bfr[j] = *(const short8*)(Bs + (wc * 64 + j * 16 + mr) * LDSS + q * 8);
        #pragma unroll
        for (int i = 0; i < 4; i++)
            #pragma unroll
            for (int j = 0; j < 4; j++)
                acc[i][j] = __builtin_amdgcn_mfma_f32_16x16x32_bf16(afr[i], bfr[j],
                                                                    acc[i][j], 0, 0, 0);
        if (!more) break;
        __syncthreads();
        *(short8*)(As + sr * LDSS + skoff) = va0;
        *(short8*)(As + (sr + 64) * LDSS + skoff) = va1;
        *(short8*)(Bs + sr * LDSS + skoff) = vb0;
        *(short8*)(Bs + (sr + 64) * LDSS + skoff) = vb1;
        __syncthreads();
        k0 = k1;
    }

    if (dotw) {
        // fused final-layer dot: z[row] += sum_col relu(acc+bias)*dotw[col]
        float bj[4], wj[4];
        #pragma unroll
        for (int j = 0; j < 4; j++) {
            int col = col0 + wc * 64 + j * 16 + mr;
            bj[j] = bias[col];
            wj[j] = dotw[col];
        }
        #pragma unroll
        for (int i = 0; i < 4; i++) {
            #pragma unroll
            for (int r = 0; r < 4; r++) {
                float p = 0.0f;
                #pragma unroll
                for (int j = 0; j < 4; j++)
                    p += fmaxf(acc[i][j][r] + bj[j], 0.0f) * wj[j];
                #pragma unroll
                for (int off = 1; off < 16; off <<= 1)
                    p += __shfl_xor(p, off, 64);   // reduce over mr within quad
                if (mr == 0)
                    atomicAdd(&z[row0 + wr * 64 + i * 16 + q * 4 + r], p);
            }
        }
        return;
    }

    if (C8) {
        // epilogue, fp8 e4m3 output (H3 for the layer-4 gather)
        #pragma unroll
        for (int j = 0; j < 4; j++) {
            int col = col0 + wc * 64 + j * 16 + mr;
            float bj = bias[col];
            #pragma unroll
            for (int i = 0; i < 4; i++) {
                int rbase = row0 + wr * 64 + i * 16 + q * 4;
                #pragma unroll
                for (int r = 0; r < 4; r++) {
                    float v = fmaxf(acc[i][j][r] + bj, 0.0f);
                    C8[(size_t)(rbase + r) * N + col] = f2fp8(v);
                }
            }
        }
        return;
    }

    // epilogue: C/D layout col=lane&15, row=q*4+reg; emit bf16
    #pragma unroll
    for (int j = 0; j < 4; j++) {
        int col = col0 + wc * 64 + j * 16 + mr;
        float bj = bias[col];
        #pragma unroll
        for (int i = 0; i < 4; i++) {
            int rbase = row0 + wr * 64 + i * 16 + q * 4;
            #pragma unroll
            for (int r = 0; r < 4; r++) {
                float v = acc[i][j][r] + bj;
                if (do_relu) v = fmaxf(v, 0.0f);
                C[(size_t)(rbase + r) * N + col] = f2bf(v);
            }
        }
    }
}

// ---------------- final: add-aggregate z + bias + sigmoid ----------------

__global__ void k_agg_final(const float* __restrict__ h, float* __restrict__ out,
                            const int* __restrict__ ell, const int* __restrict__ cnt,
                            const float* __restrict__ b5, int n) {
    int v = blockIdx.x * blockDim.x + threadIdx.x;
    if (v >= n) return;
    float dv = dinv_of(cnt, v);
    float acc = dv * h[v];
    int end = cnt[v];
    const int* r = ell + ((size_t)v << 6);
    for (int e = 0; e < end; e++) {
        int s = r[e];
        acc += dinv_of(cnt, s) * h[s];
    }
    float rr = dv * acc + b5[0];
    out[v] = 1.0f / (1.0f + expf(-rr));
}

// ---------------- launch ----------------

extern "C" void kernel_launch(void* const* d_in, const int* in_sizes, int n_in,
                              void* d_out, int out_size, void* d_ws, size_t ws_size,
                              hipStream_t stream) {
    const float* x   = (const float*)d_in[0];
    const int*   ei  = (const int*)d_in[1];
    const float* W[5] = {(const float*)d_in[2], (const float*)d_in[4], (const float*)d_in[6],
                         (const float*)d_in[8], (const float*)d_in[10]};
    const float* b[5] = {(const float*)d_in[3], (const float*)d_in[5], (const float*)d_in[7],
                         (const float*)d_in[9], (const float*)d_in[11]};
    const int n = in_sizes[0] / 16;
    const int E = in_sizes[1] / 2;

    const int* e_row = ei;          // src
    const int* e_col = ei + E;      // dst

    // workspace layout
    float* bufA_f = (float*)d_ws;                     // n*512 floats region
    float* bufB_f = bufA_f + (size_t)n * 512;         // n*512 floats region
    ushort* bufA  = (ushort*)bufA_f;                  // h (GEMM out, bf16/fp8)
    ushort* bufB  = (ushort*)bufB_f;                  // agg out (bf16)
    int*   cnt    = (int*)(bufB_f + (size_t)n * 512); // n
    int*   ell    = cnt + n;                          // n * ELLW
    ushort* wt2   = (ushort*)(ell + (size_t)n * ELLW);
    ushort* wt3   = wt2 + 64 * 128;
    ushort* wt4   = wt3 + 128 * 256;
    float* ellw   = (float*)(wt4 + 256 * 512);        // n * ELLW floats
    float* z      = ellw + (size_t)n * ELLW;          // Mpad floats

    const int Mpad = (n + GBM - 1) / GBM * GBM;       // 20096

    // ---- prep ----
    k_zero<<<(Mpad + 255) / 256, 256, 0, stream>>>(cnt, z, n, Mpad);
    k_fill_ell<<<(E + 255) / 256, 256, 0, stream>>>(e_row, e_col, cnt, ell, E,
                                                    W[1], W[2], W[3], wt2, wt3, wt4);

    // ---- layer 1: fused agg(d=16) + 16x64 GEMM + relu -> bf16 h ----
    k_l1_fused<<<(n + 63) / 64, 256, 0, stream>>>(
        (const float4*)x, bufA, ell, cnt, ellw, W[0], b[0], n);

    // ---- layer 2 ----
    k_agg_ell_bf16<<<(n + 31) / 32, 256, 0, stream>>>(
        (const short8*)bufA, (short8*)bufB, ell, cnt, ellw, n, 3);
    {
        dim3 ggrid(128 / GBN, Mpad / GBM);
        gemm_mfma<<<ggrid, 256, 0, stream>>>(bufB, wt2, b[1], bufA, nullptr,
                                             nullptr, nullptr, 64, 128, 1);
    }

    // ---- layer 3 (GEMM emits H3 as fp8 e4m3) ----
    k_agg_ell_bf16<<<(n + 15) / 16, 256, 0, stream>>>(
        (const short8*)bufA, (short8*)bufB, ell, cnt, ellw, n, 4);
    {
        dim3 ggrid(256 / GBN, Mpad / GBM);
        gemm_mfma<<<ggrid, 256, 0, stream>>>(bufB, wt3, b[2], nullptr,
                                             (unsigned char*)bufA,
                                             nullptr, nullptr, 128, 256, 1);
    }

    // ---- layer 4 (fp8 gather) + fused layer-5 dot ----
    k_agg_ell_fp8<<<(n + 7) / 8, 256, 0, stream>>>(
        (const uchar8*)bufA, (short8*)bufB, ell, cnt, ellw, n, 5);
    {
        dim3 ggrid(512 / GBN, Mpad / GBM);
        gemm_mfma<<<ggrid, 256, 0, stream>>>(bufB, wt4, b[3], nullptr, nullptr,
                                             W[4], z, 256, 512, 1);
    }

    // ---- layer 5: add-aggregate + sigmoid ----
    k_agg_final<<<(n + 255) / 256, 256, 0, stream>>>(z, (float*)d_out, ell, cnt,
                                                     b[4], n);
}

// Round 9
// 195.474 us; speedup vs baseline: 5.5956x; 1.0254x over previous
//
#include <hip/hip_runtime.h>
#include <hip/hip_bf16.h>
#include <hip/hip_fp8.h>
#include <math.h>

// GCN 5-layer: dims 16->64->128->256->512->1, N=20000, E=320000.
// Round 18: r17 base + fp8(e4m3) storage extended to H1 and H2 (was H3 only).
// All three inter-layer activations are now fp8: gather traffic 20.5/41/82 MB
// (was 41/82/164), and H2's working set (2.56 MB) now fits a per-XCD L2.
// GEMM2/3 epilogues emit fp8; layer-1 fused kernel stores fp8; all aggs use
// the fp8 gather kernel. fp32 accumulate everywhere; GEMM A/B stay bf16.

#define N_NODES 20000
#define N_EDGES 320000
#define ELLW 64   // P(in-deg >= 48) ~ 1e-10 for Poisson(16)

typedef __attribute__((ext_vector_type(8))) short short8;
typedef __attribute__((ext_vector_type(8))) unsigned char uchar8;
typedef __attribute__((ext_vector_type(4))) float f32x4;

__device__ inline ushort f2bf(float f) {
    __hip_bfloat16 h = __float2bfloat16(f);   // RNE
    return *(ushort*)&h;
}

__device__ inline float bf2f(short s) {
    union { unsigned int u; float f; } c;
    c.u = ((unsigned int)(unsigned short)s) << 16;
    return c.f;
}

__device__ inline unsigned char f2fp8(float f) {
    __hip_fp8_e4m3 q(f);
    return *reinterpret_cast<unsigned char*>(&q);
}

__device__ inline float fp82f(unsigned char u) {
    __hip_fp8_e4m3 q = *reinterpret_cast<__hip_fp8_e4m3*>(&u);
    return (float)q;
}

__device__ __forceinline__ float dinv_of(const int* __restrict__ cnt, int v) {
    return rsqrtf((float)(cnt[v] + 1));       // in-degree + self-loop
}

// ---------------- prep: zero cnt + z ----------------

__global__ void k_zero(int* __restrict__ cnt, float* __restrict__ z, int n, int mpad) {
    int i = blockIdx.x * blockDim.x + threadIdx.x;
    if (i < n) cnt[i] = 0;
    if (i < mpad) z[i] = 0.0f;
}

// ---------------- ELL build + weight transposes (ride the same grid) --------

__global__ void k_fill_ell(const int* __restrict__ row, const int* __restrict__ col,
                           int* __restrict__ cnt, int* __restrict__ ell, int E,
                           const float* __restrict__ W2, const float* __restrict__ W3,
                           const float* __restrict__ W4,
                           ushort* __restrict__ T2, ushort* __restrict__ T3,
                           ushort* __restrict__ T4) {
    int e = blockIdx.x * blockDim.x + threadIdx.x;
    if (e < 172032) {
        const float* W; ushort* T; int K, N, j;
        if (e < 8192)        { W = W2; T = T2; K = 64;  N = 128; j = e; }
        else if (e < 40960)  { W = W3; T = T3; K = 128; N = 256; j = e - 8192; }
        else                 { W = W4; T = T4; K = 256; N = 512; j = e - 40960; }
        int nn = j / K, kk = j - nn * K;
        T[(size_t)nn * K + kk] = f2bf(W[(size_t)kk * N + nn]);
    }
    if (e >= E) return;
    int s = row[e], d = col[e];
    int pos = atomicAdd(&cnt[d], 1);
    ell[((size_t)d << 6) + pos] = s;
}

// ---------------- layer 1 fused: agg(d=16, fp32) + GEMM 16x64 + relu --------
// Lane 0 of each node group also stores w_full = dinv_s * dv * inv_cnt.
// Output H1 is fp8 e4m3.

__global__ __launch_bounds__(256) void k_l1_fused(const float4* __restrict__ x,
                                                  unsigned char* __restrict__ h_out,
                                                  const int* __restrict__ ell,
                                                  const int* __restrict__ cnt,
                                                  float* __restrict__ ellw,
                                                  const float* __restrict__ W,
                                                  const float* __restrict__ b, int n) {
    __shared__ float sW[16 * 64];
    __shared__ float sb[64];
    __shared__ float sagg[64][17];    // padded: avoid bank conflicts
    int tid = threadIdx.x;
    #pragma unroll
    for (int i = tid; i < 1024; i += 256) sW[i] = W[i];
    if (tid < 64) sb[tid] = b[tid];

    int grp = tid >> 2;               // node within block
    int lane = tid & 3;               // float4 lane (4 feats each)
    int v = blockIdx.x * 64 + grp;
    if (v < n) {
        float dv = dinv_of(cnt, v);
        int end = cnt[v];
        float inv_cnt = 1.0f / (float)(end + 1);
        float sc = dv * inv_cnt;
        const int* r = ell + ((size_t)v << 6);
        float* wrow = ellw + ((size_t)v << 6);
        float4 hv = x[(size_t)v * 4 + lane];
        float4 acc = make_float4(dv * hv.x, dv * hv.y, dv * hv.z, dv * hv.w);
        int e = 0;
        for (; e + 8 <= end; e += 8) {
            int s0 = r[e],     s1 = r[e + 1], s2 = r[e + 2], s3 = r[e + 3];
            int s4 = r[e + 4], s5 = r[e + 5], s6 = r[e + 6], s7 = r[e + 7];
            float4 h0 = x[(size_t)s0 * 4 + lane];
            float4 h1 = x[(size_t)s1 * 4 + lane];
            float4 h2 = x[(size_t)s2 * 4 + lane];
            float4 h3 = x[(size_t)s3 * 4 + lane];
            float4 h4 = x[(size_t)s4 * 4 + lane];
            float4 h5 = x[(size_t)s5 * 4 + lane];
            float4 h6 = x[(size_t)s6 * 4 + lane];
            float4 h7 = x[(size_t)s7 * 4 + lane];
            float w0 = dinv_of(cnt, s0), w1 = dinv_of(cnt, s1);
            float w2 = dinv_of(cnt, s2), w3 = dinv_of(cnt, s3);
            float w4 = dinv_of(cnt, s4), w5 = dinv_of(cnt, s5);
            float w6 = dinv_of(cnt, s6), w7 = dinv_of(cnt, s7);
            if (lane == 0) {
                *(float4*)(wrow + e)     = make_float4(w0 * sc, w1 * sc, w2 * sc, w3 * sc);
                *(float4*)(wrow + e + 4) = make_float4(w4 * sc, w5 * sc, w6 * sc, w7 * sc);
            }
            acc.x += w0 * h0.x + w1 * h1.x + w2 * h2.x + w3 * h3.x
                   + w4 * h4.x + w5 * h5.x + w6 * h6.x + w7 * h7.x;
            acc.y += w0 * h0.y + w1 * h1.y + w2 * h2.y + w3 * h3.y
                   + w4 * h4.y + w5 * h5.y + w6 * h6.y + w7 * h7.y;
            acc.z += w0 * h0.z + w1 * h1.z + w2 * h2.z + w3 * h3.z
                   + w4 * h4.z + w5 * h5.z + w6 * h6.z + w7 * h7.z;
            acc.w += w0 * h0.w + w1 * h1.w + w2 * h2.w + w3 * h3.w
                   + w4 * h4.w + w5 * h5.w + w6 * h6.w + w7 * h7.w;
        }
        for (; e + 4 <= end; e += 4) {
            int s0 = r[e], s1 = r[e + 1], s2 = r[e + 2], s3 = r[e + 3];
            float4 h0 = x[(size_t)s0 * 4 + lane];
            float4 h1 = x[(size_t)s1 * 4 + lane];
            float4 h2 = x[(size_t)s2 * 4 + lane];
            float4 h3 = x[(size_t)s3 * 4 + lane];
            float w0 = dinv_of(cnt, s0), w1 = dinv_of(cnt, s1);
            float w2 = dinv_of(cnt, s2), w3 = dinv_of(cnt, s3);
            if (lane == 0)
                *(float4*)(wrow + e) = make_float4(w0 * sc, w1 * sc, w2 * sc, w3 * sc);
            acc.x += w0 * h0.x + w1 * h1.x + w2 * h2.x + w3 * h3.x;
            acc.y += w0 * h0.y + w1 * h1.y + w2 * h2.y + w3 * h3.y;
            acc.z += w0 * h0.z + w1 * h1.z + w2 * h2.z + w3 * h3.z;
            acc.w += w0 * h0.w + w1 * h1.w + w2 * h2.w + w3 * h3.w;
        }
        for (; e < end; e++) {
            int s = r[e];
            float w = dinv_of(cnt, s);
            if (lane == 0) wrow[e] = w * sc;
            float4 hs = x[(size_t)s * 4 + lane];
            acc.x += w * hs.x; acc.y += w * hs.y; acc.z += w * hs.z; acc.w += w * hs.w;
        }
        sagg[grp][lane * 4 + 0] = acc.x * sc;
        sagg[grp][lane * 4 + 1] = acc.y * sc;
        sagg[grp][lane * 4 + 2] = acc.z * sc;
        sagg[grp][lane * 4 + 3] = acc.w * sc;
    }
    __syncthreads();

    int vg = tid >> 2;
    int c0 = (tid & 3) * 16;
    int vout = blockIdx.x * 64 + vg;
    if (vout >= n) return;
    float o[16];
    #pragma unroll
    for (int jj = 0; jj < 16; jj++) o[jj] = sb[c0 + jj];
    #pragma unroll
    for (int k = 0; k < 16; k++) {
        float a = sagg[vg][k];
        #pragma unroll
        for (int jj = 0; jj < 16; jj++) o[jj] += a * sW[k * 64 + c0 + jj];
    }
    uchar8 p0, p1;
    #pragma unroll
    for (int jj = 0; jj < 8; jj++) p0[jj] = f2fp8(fmaxf(o[jj], 0.0f));
    #pragma unroll
    for (int jj = 0; jj < 8; jj++) p1[jj] = f2fp8(fmaxf(o[jj + 8], 0.0f));
    *(uchar8*)(h_out + (size_t)vout * 64 + c0) = p0;
    *(uchar8*)(h_out + (size_t)vout * 64 + c0 + 8) = p1;
}

// ---------------- fp8-input ELL aggregation (layers 2..4) -------------------
// out = selfw*hv + sum ellw[e]*hs; selfw = inv_cnt^2. bf16 output for GEMM A.

__global__ void k_agg_ell_fp8(const uchar8* __restrict__ h, short8* __restrict__ out,
                              const int* __restrict__ ell, const int* __restrict__ cnt,
                              const float* __restrict__ ellw, int n, int g_shift) {
    int g = 1 << g_shift;                        // lanes per node = d/8
    int grp = threadIdx.x >> g_shift;
    int lane = threadIdx.x & (g - 1);
    int gpb = blockDim.x >> g_shift;
    int v = blockIdx.x * gpb + grp;
    if (v >= n) return;
    int end = cnt[v];
    float inv_cnt = 1.0f / (float)(end + 1);
    float selfw = inv_cnt * inv_cnt;
    const int* r = ell + ((size_t)v << 6);
    const float* wrow = ellw + ((size_t)v << 6);

    float acc[8];
    uchar8 hv = h[(size_t)v * g + lane];
    #pragma unroll
    for (int i = 0; i < 8; i++) acc[i] = selfw * fp82f(hv[i]);

    int e = 0;
    for (; e + 8 <= end; e += 8) {
        int s0 = r[e],     s1 = r[e + 1], s2 = r[e + 2], s3 = r[e + 3];
        int s4 = r[e + 4], s5 = r[e + 5], s6 = r[e + 6], s7 = r[e + 7];
        float4 wA = *(const float4*)(wrow + e);
        float4 wB = *(const float4*)(wrow + e + 4);
        uchar8 h0 = h[(size_t)s0 * g + lane];
        uchar8 h1 = h[(size_t)s1 * g + lane];
        uchar8 h2 = h[(size_t)s2 * g + lane];
        uchar8 h3 = h[(size_t)s3 * g + lane];
        uchar8 h4 = h[(size_t)s4 * g + lane];
        uchar8 h5 = h[(size_t)s5 * g + lane];
        uchar8 h6 = h[(size_t)s6 * g + lane];
        uchar8 h7 = h[(size_t)s7 * g + lane];
        #pragma unroll
        for (int i = 0; i < 8; i++)
            acc[i] += wA.x * fp82f(h0[i]) + wA.y * fp82f(h1[i])
                    + wA.z * fp82f(h2[i]) + wA.w * fp82f(h3[i])
                    + wB.x * fp82f(h4[i]) + wB.y * fp82f(h5[i])
                    + wB.z * fp82f(h6[i]) + wB.w * fp82f(h7[i]);
    }
    for (; e + 4 <= end; e += 4) {
        int s0 = r[e], s1 = r[e + 1], s2 = r[e + 2], s3 = r[e + 3];
        float4 wA = *(const float4*)(wrow + e);
        uchar8 h0 = h[(size_t)s0 * g + lane];
        uchar8 h1 = h[(size_t)s1 * g + lane];
        uchar8 h2 = h[(size_t)s2 * g + lane];
        uchar8 h3 = h[(size_t)s3 * g + lane];
        #pragma unroll
        for (int i = 0; i < 8; i++)
            acc[i] += wA.x * fp82f(h0[i]) + wA.y * fp82f(h1[i])
                    + wA.z * fp82f(h2[i]) + wA.w * fp82f(h3[i]);
    }
    for (; e < end; e++) {
        int s0 = r[e];
        float w0 = wrow[e];
        uchar8 h0 = h[(size_t)s0 * g + lane];
        #pragma unroll
        for (int i = 0; i < 8; i++) acc[i] += w0 * fp82f(h0[i]);
    }
    short8 o;
    #pragma unroll
    for (int i = 0; i < 8; i++) o[i] = (short)f2bf(acc[i]);
    out[(size_t)v * g + lane] = o;
}

// ---------------- MFMA GEMM: C = relu(A[M,K] @ Wt[N,K]^T + bias) ------------
// M padded to 128 multiple, K/N exact multiples -> no bounds checks.
// C8 != nullptr: emit fp8 e4m3. dotw != nullptr: fused final dot into z.

#define GBM 128
#define GBN 128
#define GBK 32
#define LDSS 40   // LDS row stride in elements (80B, 16B-aligned)

__global__ __launch_bounds__(256) void gemm_mfma(const ushort* __restrict__ A,
                                                 const ushort* __restrict__ Wt,
                                                 const float* __restrict__ bias,
                                                 ushort* __restrict__ C,
                                                 unsigned char* __restrict__ C8,
                                                 const float* __restrict__ dotw,
                                                 float* __restrict__ z,
                                                 int K, int N, int do_relu) {
    __shared__ ushort As[GBM * LDSS];
    __shared__ ushort Bs[GBN * LDSS];
    int tid = threadIdx.x;
    int wave = tid >> 6;
    int lane = tid & 63;
    int wr = wave >> 1, wc = wave & 1;
    int q = lane >> 4;          // quad 0..3
    int mr = lane & 15;
    int row0 = blockIdx.y * GBM;
    int col0 = blockIdx.x * GBN;

    int sr = tid >> 2;          // staging row 0..63 (and sr+64)
    int skoff = (tid & 3) * 8;  // staging k offset

    f32x4 acc[4][4];
    #pragma unroll
    for (int i = 0; i < 4; i++)
        #pragma unroll
        for (int j = 0; j < 4; j++) acc[i][j] = (f32x4){0.f, 0.f, 0.f, 0.f};

    short8 va0, va1, vb0, vb1;
    int gn0 = col0 + sr, gn1 = col0 + sr + 64;

    {
        va0 = *(const short8*)(A + (size_t)(row0 + sr) * K + skoff);
        va1 = *(const short8*)(A + (size_t)(row0 + sr + 64) * K + skoff);
        vb0 = *(const short8*)(Wt + (size_t)gn0 * K + skoff);
        vb1 = *(const short8*)(Wt + (size_t)gn1 * K + skoff);
        *(short8*)(As + sr * LDSS + skoff) = va0;
        *(short8*)(As + (sr + 64) * LDSS + skoff) = va1;
        *(short8*)(Bs + sr * LDSS + skoff) = vb0;
        *(short8*)(Bs + (sr + 64) * LDSS + skoff) = vb1;
    }
    __syncthreads();

    for (int k0 = 0;;) {
        int k1 = k0 + GBK;
        bool more = (k1 < K);
        if (more) {                       // prefetch next tile into registers
            int gk = k1 + skoff;
            va0 = *(const short8*)(A + (size_t)(row0 + sr) * K + gk);
            va1 = *(const short8*)(A + (size_t)(row0 + sr + 64) * K + gk);
            vb0 = *(const short8*)(Wt + (size_t)gn0 * K + gk);
            vb1 = *(const short8*)(Wt + (size_t)gn1 * K + gk);
        }
        short8 afr[4], bfr[4];
        #pragma unroll
        for (int i = 0; i < 4; i++)
            afr[i] = *(const short8*)(As + (wr * 64 + i * 16 + mr) * LDSS + q * 8);
        #pragma unroll
        for (int j = 0; j < 4; j++)
            bfr[j] = *(const short8*)(Bs + (wc * 64 + j * 16 + mr) * LDSS + q * 8);
        #pragma unroll
        for (int i = 0; i < 4; i++)
            #pragma unroll
            for (int j = 0; j < 4; j++)
                acc[i][j] = __builtin_amdgcn_mfma_f32_16x16x32_bf16(afr[i], bfr[j],
                                                                    acc[i][j], 0, 0, 0);
        if (!more) break;
        __syncthreads();
        *(short8*)(As + sr * LDSS + skoff) = va0;
        *(short8*)(As + (sr + 64) * LDSS + skoff) = va1;
        *(short8*)(Bs + sr * LDSS + skoff) = vb0;
        *(short8*)(Bs + (sr + 64) * LDSS + skoff) = vb1;
        __syncthreads();
        k0 = k1;
    }

    if (dotw) {
        // fused final-layer dot: z[row] += sum_col relu(acc+bias)*dotw[col]
        float bj[4], wj[4];
        #pragma unroll
        for (int j = 0; j < 4; j++) {
            int col = col0 + wc * 64 + j * 16 + mr;
            bj[j] = bias[col];
            wj[j] = dotw[col];
        }
        #pragma unroll
        for (int i = 0; i < 4; i++) {
            #pragma unroll
            for (int r = 0; r < 4; r++) {
                float p = 0.0f;
                #pragma unroll
                for (int j = 0; j < 4; j++)
                    p += fmaxf(acc[i][j][r] + bj[j], 0.0f) * wj[j];
                #pragma unroll
                for (int off = 1; off < 16; off <<= 1)
                    p += __shfl_xor(p, off, 64);   // reduce over mr within quad
                if (mr == 0)
                    atomicAdd(&z[row0 + wr * 64 + i * 16 + q * 4 + r], p);
            }
        }
        return;
    }

    if (C8) {
        // epilogue, fp8 e4m3 output (H for the next layer's gather)
        #pragma unroll
        for (int j = 0; j < 4; j++) {
            int col = col0 + wc * 64 + j * 16 + mr;
            float bj = bias[col];
            #pragma unroll
            for (int i = 0; i < 4; i++) {
                int rbase = row0 + wr * 64 + i * 16 + q * 4;
                #pragma unroll
                for (int r = 0; r < 4; r++) {
                    float v = fmaxf(acc[i][j][r] + bj, 0.0f);
                    C8[(size_t)(rbase + r) * N + col] = f2fp8(v);
                }
            }
        }
        return;
    }

    // epilogue: C/D layout col=lane&15, row=q*4+reg; emit bf16
    #pragma unroll
    for (int j = 0; j < 4; j++) {
        int col = col0 + wc * 64 + j * 16 + mr;
        float bj = bias[col];
        #pragma unroll
        for (int i = 0; i < 4; i++) {
            int rbase = row0 + wr * 64 + i * 16 + q * 4;
            #pragma unroll
            for (int r = 0; r < 4; r++) {
                float v = acc[i][j][r] + bj;
                if (do_relu) v = fmaxf(v, 0.0f);
                C[(size_t)(rbase + r) * N + col] = f2bf(v);
            }
        }
    }
}

// ---------------- final: add-aggregate z + bias + sigmoid ----------------

__global__ void k_agg_final(const float* __restrict__ h, float* __restrict__ out,
                            const int* __restrict__ ell, const int* __restrict__ cnt,
                            const float* __restrict__ b5, int n) {
    int v = blockIdx.x * blockDim.x + threadIdx.x;
    if (v >= n) return;
    float dv = dinv_of(cnt, v);
    float acc = dv * h[v];
    int end = cnt[v];
    const int* r = ell + ((size_t)v << 6);
    for (int e = 0; e < end; e++) {
        int s = r[e];
        acc += dinv_of(cnt, s) * h[s];
    }
    float rr = dv * acc + b5[0];
    out[v] = 1.0f / (1.0f + expf(-rr));
}

// ---------------- launch ----------------

extern "C" void kernel_launch(void* const* d_in, const int* in_sizes, int n_in,
                              void* d_out, int out_size, void* d_ws, size_t ws_size,
                              hipStream_t stream) {
    const float* x   = (const float*)d_in[0];
    const int*   ei  = (const int*)d_in[1];
    const float* W[5] = {(const float*)d_in[2], (const float*)d_in[4], (const float*)d_in[6],
                         (const float*)d_in[8], (const float*)d_in[10]};
    const float* b[5] = {(const float*)d_in[3], (const float*)d_in[5], (const float*)d_in[7],
                         (const float*)d_in[9], (const float*)d_in[11]};
    const int n = in_sizes[0] / 16;
    const int E = in_sizes[1] / 2;

    const int* e_row = ei;          // src
    const int* e_col = ei + E;      // dst

    // workspace layout
    float* bufA_f = (float*)d_ws;                     // n*512 floats region
    float* bufB_f = bufA_f + (size_t)n * 512;         // n*512 floats region
    ushort* bufA  = (ushort*)bufA_f;                  // h (GEMM out, fp8 here)
    ushort* bufB  = (ushort*)bufB_f;                  // agg out (bf16)
    int*   cnt    = (int*)(bufB_f + (size_t)n * 512); // n
    int*   ell    = cnt + n;                          // n * ELLW
    ushort* wt2   = (ushort*)(ell + (size_t)n * ELLW);
    ushort* wt3   = wt2 + 64 * 128;
    ushort* wt4   = wt3 + 128 * 256;
    float* ellw   = (float*)(wt4 + 256 * 512);        // n * ELLW floats
    float* z      = ellw + (size_t)n * ELLW;          // Mpad floats

    const int Mpad = (n + GBM - 1) / GBM * GBM;       // 20096

    // ---- prep ----
    k_zero<<<(Mpad + 255) / 256, 256, 0, stream>>>(cnt, z, n, Mpad);
    k_fill_ell<<<(E + 255) / 256, 256, 0, stream>>>(e_row, e_col, cnt, ell, E,
                                                    W[1], W[2], W[3], wt2, wt3, wt4);

    // ---- layer 1: fused agg(d=16) + 16x64 GEMM + relu -> fp8 H1 ----
    k_l1_fused<<<(n + 63) / 64, 256, 0, stream>>>(
        (const float4*)x, (unsigned char*)bufA, ell, cnt, ellw, W[0], b[0], n);

    // ---- layer 2 (fp8 gather d=64) ----
    k_agg_ell_fp8<<<(n + 31) / 32, 256, 0, stream>>>(
        (const uchar8*)bufA, (short8*)bufB, ell, cnt, ellw, n, 3);
    {
        dim3 ggrid(128 / GBN, Mpad / GBM);
        gemm_mfma<<<ggrid, 256, 0, stream>>>(bufB, wt2, b[1], nullptr,
                                             (unsigned char*)bufA,
                                             nullptr, nullptr, 64, 128, 1);
    }

    // ---- layer 3 (fp8 gather d=128) ----
    k_agg_ell_fp8<<<(n + 15) / 16, 256, 0, stream>>>(
        (const uchar8*)bufA, (short8*)bufB, ell, cnt, ellw, n, 4);
    {
        dim3 ggrid(256 / GBN, Mpad / GBM);
        gemm_mfma<<<ggrid, 256, 0, stream>>>(bufB, wt3, b[2], nullptr,
                                             (unsigned char*)bufA,
                                             nullptr, nullptr, 128, 256, 1);
    }

    // ---- layer 4 (fp8 gather d=256) + fused layer-5 dot ----
    k_agg_ell_fp8<<<(n + 7) / 8, 256, 0, stream>>>(
        (const uchar8*)bufA, (short8*)bufB, ell, cnt, ellw, n, 5);
    {
        dim3 ggrid(512 / GBN, Mpad / GBM);
        gemm_mfma<<<ggrid, 256, 0, stream>>>(bufB, wt4, b[3], nullptr, nullptr,
                                             W[4], z, 256, 512, 1);
    }

    // ---- layer 5: add-aggregate + sigmoid ----
    k_agg_final<<<(n + 255) / 256, 256, 0, stream>>>(z, (float*)d_out, ell, cnt,
                                                     b[4], n);
}